// Round 10
// baseline (631.276 us; speedup 1.0000x reference)
//
#include <hip/hip_runtime.h>
#include <math.h>

#define NNODE 10000
#define NEDGE 160000
#define KNB   16
#define K1    17
#define NT    10
#define TN    10
#define DF    128
#define CAP   64
#define NEG_BIG (-1e9f)

#define LOGQ2      (-3.32192809489f)   /* log2(0.1) */
#define KB_SCALE   (-14.4269504089f)   /* -10*log2e  */
#define CR_SCALE   (28.8539008178f)    /* +20*log2e  */
#define G_SCALE    (-0.069314718056f)  /* -ln2/10    */
#define LN2        0.69314718056f
#define TINYF      1e-30f

#if defined(__has_builtin)
#if __has_builtin(__builtin_amdgcn_exp2f)
#define EXP2F(x) __builtin_amdgcn_exp2f(x)
#endif
#if __has_builtin(__builtin_amdgcn_rcpf)
#define RCPF(x) __builtin_amdgcn_rcpf(x)
#endif
#endif
#ifndef EXP2F
#define EXP2F(x) __expf((x) * LN2)
#endif
#ifndef RCPF
#define RCPF(x) (1.0f / (x))
#endif
#define LOG2F(x) __log2f(x)

// Compiler-only barrier: DS ops from one wave execute IN ORDER in the LDS
// pipeline; compiler still emits lgkmcnt(N) before VALU consumes read data.
#define CBAR() asm volatile("" ::: "memory")

__device__ __forceinline__ float2 pk_add(float2 a, float2 b) { return make_float2(a.x + b.x, a.y + b.y); }
__device__ __forceinline__ float2 pk_sub(float2 a, float2 b) { return make_float2(a.x - b.x, a.y - b.y); }
__device__ __forceinline__ float2 pk_mul(float2 a, float2 b) { return make_float2(a.x * b.x, a.y * b.y); }
__device__ __forceinline__ float2 pk_max(float2 a, float2 b) { return make_float2(fmaxf(a.x, b.x), fmaxf(a.y, b.y)); }
__device__ __forceinline__ float2 pk_fma(float2 a, float2 b, float2 c) { return make_float2(fmaf(a.x, b.x, c.x), fmaf(a.y, b.y, c.y)); }
__device__ __forceinline__ float2 pk_exp2(float2 a) { return make_float2(EXP2F(a.x), EXP2F(a.y)); }
__device__ __forceinline__ float clamp120(float x) { return fminf(120.f, fmaxf(-120.f, x)); }

__device__ __forceinline__ int detect_wide(const int* ei) {
  int z = 0;
#pragma unroll
  for (int i = 0; i < 32; ++i) z |= ei[2 * i + 1];
  return z == 0;
}

// ---------- fused: edge bucketing (transposed ebuf) + feature dots + template stats ----------
__global__ void __launch_bounds__(256) k_prep(const int* __restrict__ ei,
                                              int* cnt, int* ebuf,
                                              const float* __restrict__ x,
                                              const float* __restrict__ tf,
                                              const float* __restrict__ tmpl,
                                              float* __restrict__ dots,
                                              float* __restrict__ nxv,
                                              float* __restrict__ nF2,
                                              float* __restrict__ Bq) {
  __shared__ float xs[64][DF];
  const int tid = threadIdx.x;
  if (blockIdx.x < 625) {          // hist: 625*256 == NEDGE
    int e = blockIdx.x * 256 + tid;
    int wide = detect_wide(ei);
    int s = wide ? ei[2 * e] : ei[e];
    int pos = atomicAdd(&cnt[s], 1);
    if (pos < CAP) ebuf[pos * NNODE + s] = e;   // transposed: coalesced select reads
    return;
  }
  const int db = blockIdx.x - 625;
  if (db == 0 && tid < NT * TN) {  // template stats, once
    const float* fp = tf + (size_t)tid * DF;
    float s = 0.f;
    for (int d = 0; d < DF; ++d) { float v = fp[d]; s += v * v; }
    nF2[tid] = s;
    const float* cp = tmpl + (size_t)tid * TN;
    float s2 = 0.f;
    for (int c = 0; c < TN; ++c) { float v = cp[c]; s2 += v * v; }
    Bq[tid] = 0.1f * s2;
  }
  const int nb = db * 64;
  const int nvalid = (NNODE - nb) < 64 ? (NNODE - nb) : 64;
  {
    const float4* xg = (const float4*)(x + (size_t)nb * DF);
    float4* xl = (float4*)&xs[0][0];
    for (int i = tid; i < nvalid * (DF / 4); i += 256) xl[i] = xg[i];
  }
  __syncthreads();
  for (int o = tid; o < nvalid * (NT * TN); o += 256) {
    int n = o / (NT * TN);
    int tb = o - n * (NT * TN);
    const float4* fp = (const float4*)(tf + (size_t)tb * DF);
    const float4* xp = (const float4*)&xs[n][0];
    float s = 0.f;
#pragma unroll
    for (int d = 0; d < DF / 4; ++d) {
      float4 a = xp[d], f = fp[d];
      s += a.x * f.x + a.y * f.y + a.z * f.z + a.w * f.w;
    }
    dots[(size_t)(nb + n) * (NT * TN) + tb] = s;
  }
  if (tid < nvalid) {
    const float4* xp = (const float4*)&xs[tid][0];
    float s = 0.f;
#pragma unroll
    for (int d = 0; d < DF / 4; ++d) {
      float4 a = xp[d];
      s += a.x * a.x + a.y * a.y + a.z * a.z + a.w * a.w;
    }
    nxv[nb + tid] = s;
  }
}

// ---------- per node, keep 16 smallest edge ids (coalesced ebuf reads) ----------
__global__ void k_select(const int* ei, const int* cnt, const int* ebuf,
                         int* nbrs, int* kcnt, int* Sg) {
  int i = blockIdx.x * blockDim.x + threadIdx.x;
  if (i >= NNODE) return;
  int wide = detect_wide(ei);
  int c = cnt[i]; c = c > CAP ? CAP : c;
  int best[KNB];
  int m = 0;
  for (int j = 0; j < c; ++j) {
    int e = ebuf[j * NNODE + i];
    if (m < KNB) {
      int p = m++;
      while (p > 0 && best[p - 1] > e) { best[p] = best[p - 1]; --p; }
      best[p] = e;
    } else if (e < best[KNB - 1]) {
      int p = KNB - 1;
      while (p > 0 && best[p - 1] > e) { best[p] = best[p - 1]; --p; }
      best[p] = e;
    }
  }
  kcnt[i] = m;
  Sg[i * K1 + 0] = i;
  for (int j = 0; j < KNB; ++j) {
    int v = 0;
    if (j < m) {
      int e = best[j];
      v = wide ? ei[2 * (NEDGE + e)] : ei[NEDGE + e];
    }
    nbrs[i * KNB + j] = v;
    Sg[i * K1 + 1 + j] = v;
  }
}

// ---------- FGW main: block = node, 2 waves x 5 pairs; inline C1 bitmasks ----------
__global__ void __launch_bounds__(128, 3) k_main(
    const float* __restrict__ tmpl,
    const int* __restrict__ kcnt, const int* __restrict__ Sg,
    const int* __restrict__ nbrs,
    const float* __restrict__ dots, const float* __restrict__ nxv,
    const float* __restrict__ nF2, const float* __restrict__ Bq,
    float* __restrict__ out)
{
  __shared__ float KT[2 * 5 * 204 + 48];  // pair stride 204 ≡ 12 mod 32; +48 pad for dummy rows
  __shared__ float fL[2][5][20];
  __shared__ float gL[2][5][12];
  __shared__ float uL[2][5][20];          // b64 pairs (u_j, u_{10+j})
  __shared__ float wL[2][5][12];
  __shared__ float accL[2][5][TN];

  const int wv = threadIdx.x >> 6;       // 0..1 = template half
  const int lane = threadIdx.x & 63;
  int p = lane / 10;
  const int b = lane - p * 10;
  const bool act = (p < 5);
  if (!act) p = 4;
  const int node = blockIdx.x;           // wave-uniform
  const int t = wv * 5 + p;
  const int tb = t * TN + b;
  float* KTp = &KT[(wv * 5 + p) * 204];

  const int kc = kcnt[node];
  const float cnt1 = (float)(1 + kc);
  const float inv_cnt1 = 1.f / cnt1;
  const float logp2v = -LOG2F(cnt1);
  const float lp2_r0 = ((b == 0) || (b - 1 < kc)) ? logp2v : NEG_BIG;  // row b
  const float lp2_r1 = ((9 + b) < kc) ? logp2v : NEG_BIG;              // row 10+b (b>=7: dummy)

  // ---- local node set ----
  int S_arr[K1];
#pragma unroll
  for (int a = 0; a < K1; ++a) S_arr[a] = Sg[node * K1 + a];

  // ---- inline C1 row bitmask: lane a (<17) computes row a; lift to SGPRs ----
  const unsigned int vmask = (kc >= KNB) ? 0x1FFFFu : ((2u << kc) - 1u);
  unsigned int mybits = 0;
  if (lane < K1) {
    bool va = (lane == 0) || (lane - 1 < kc);
    if (va) {
      int u = S_arr[lane];
      int ku = kcnt[u];
      const int* np = nbrs + (size_t)u * KNB;
      for (int j = 0; j < ku; ++j) {
        int w = np[j];
#pragma unroll
        for (int c = 0; c < K1; ++c) mybits |= (S_arr[c] == w) ? (1u << c) : 0u;
      }
      mybits &= vmask;
    }
  }
  unsigned int bw[K1];   // wave-uniform (SGPR) row masks
#pragma unroll
  for (int a = 0; a < K1; ++a)
    bw[a] = (unsigned int)__builtin_amdgcn_readlane((int)mybits, a);

  float2 c2v[5];
  {
    const float2* cp = (const float2*)(tmpl + (size_t)tb * TN);
#pragma unroll
    for (int j = 0; j < 5; ++j) c2v[j] = cp[j];
  }
  const float Bb = Bq[tb];
  const float nf2b = nF2[tb];

  float2 Kb2v[8]; float kb16;           // (2i,2i+1) pairing for log phase
  float2 Tp2[10];                       // (j, 10+j) pairing; .y=0 for j>=7 (dummy rows)
#pragma unroll
  for (int j = 0; j < 10; ++j) Tp2[j] = make_float2(0.f, 0.f);
#pragma unroll
  for (int a = 0; a < K1; ++a) {
    bool va = (a == 0) || (a - 1 < kc);
    int sa = S_arr[a];
    float Ma = (va ? (nxv[sa] - 2.f * dots[(size_t)sa * (NT * TN) + tb]) : 0.f) + nf2b;
    float ag = (float)__popc(bw[a]) * inv_cnt1;
    float base = 0.5f * Ma + ag + Bb;
    float kv = KB_SCALE * base;
    float tv = va ? (inv_cnt1 * 0.1f) : 0.f;
    if (a == 16) kb16 = kv;
    else if (a & 1) Kb2v[a >> 1].y = kv;
    else Kb2v[a >> 1].x = kv;
    if (a < 10) Tp2[a].x = tv; else Tp2[a - 10].y = tv;
  }

  float2 Kc2v[8]; float k16 = 0.f;
  float2 Kr0v[5], Kr1v[5];
  float2 gr[5];
  float g2 = 0.f, fr0 = 0.f, fr1 = 0.f;

#pragma unroll 1
  for (int k = 0; k < 6; ++k) {
    // ---- stage Tp columns into KT (row-major, [a][b]) ----
    if (act) {
#pragma unroll
      for (int a = 0; a < K1; ++a)
        KTp[a * 12 + b] = (a < 10) ? Tp2[a].x : Tp2[a - 10].y;
    }
    CBAR();
    // ---- R = Tp @ C2^T (split chains) ----
    float R[K1];
#pragma unroll
    for (int c = 0; c < K1; ++c) {
      const float* row = &KTp[c * 12];
      float4 u0 = *(const float4*)row;
      float4 u1 = *(const float4*)(row + 4);
      float2 u2 = *(const float2*)(row + 8);
      float2 accA = pk_mul(make_float2(u0.x, u0.y), c2v[0]);
      accA = pk_fma(make_float2(u0.z, u0.w), c2v[1], accA);
      float2 accB = pk_mul(make_float2(u1.x, u1.y), c2v[2]);
      accB = pk_fma(make_float2(u1.z, u1.w), c2v[3], accB);
      accA = pk_fma(u2, c2v[4], accA);
      accA = pk_add(accA, accB);
      R[c] = accA.x + accA.y;
    }
    // ---- cross = C1 @ R via wave-uniform bitmasks → logK column ----
#pragma unroll
    for (int a = 0; a < K1; ++a) {
      float cr = 0.f;
      unsigned int m = bw[a];
      if (m) {
#pragma unroll
        for (int c = 0; c < K1; ++c)
          if (m & (1u << c)) cr += R[c];
      }
      float base = (a == 16) ? kb16 : ((a & 1) ? Kb2v[a >> 1].y : Kb2v[a >> 1].x);
      float val = base + CR_SCALE * cr;
      if (a == 16) k16 = val;
      else if (a & 1) Kc2v[a >> 1].y = val;
      else Kc2v[a >> 1].x = val;
    }

    if (k == 5) {  // final distance
      float acc = 0.f;
#pragma unroll
      for (int a = 0; a < K1; ++a) {
        bool va = (a == 0) || (a - 1 < kc);
        int sa = S_arr[a];
        float Ma = (va ? (nxv[sa] - 2.f * dots[(size_t)sa * (NT * TN) + tb]) : 0.f) + nf2b;
        float kcv = (a == 16) ? k16 : ((a & 1) ? Kc2v[a >> 1].y : Kc2v[a >> 1].x);
        float tpv = (a < 10) ? Tp2[a].x : Tp2[a - 10].y;
        acc += tpv * (0.25f * Ma + 0.5f * (G_SCALE * kcv));
      }
      if (act) accL[wv][p][b] = acc;
      CBAR();
      if (lane < 5) {
        float s = 0.f;
#pragma unroll
        for (int j = 0; j < TN; ++j) s += accL[wv][lane][j];
        out[node * NT + wv * 5 + lane] = s;
      }
      return;
    }

    // ---- stage logK, read back rows b and 10+b ----
    CBAR();
    if (act) {
#pragma unroll
      for (int a = 0; a < 16; ++a) KTp[a * 12 + b] = (a & 1) ? Kc2v[a >> 1].y : Kc2v[a >> 1].x;
      KTp[16 * 12 + b] = k16;
    }
    CBAR();
    {
      const float* r0 = &KTp[b * 12];
      float4 u0 = *(const float4*)r0;
      float4 u1 = *(const float4*)(r0 + 4);
      float2 u2 = *(const float2*)(r0 + 8);
      Kr0v[0] = make_float2(u0.x, u0.y); Kr0v[1] = make_float2(u0.z, u0.w);
      Kr0v[2] = make_float2(u1.x, u1.y); Kr0v[3] = make_float2(u1.z, u1.w);
      Kr0v[4] = u2;
      const float* r1 = &KTp[(10 + b) * 12];  // b>=7: in-bounds junk (finite), row is dummy
      float4 w0 = *(const float4*)r1;
      float4 w1 = *(const float4*)(r1 + 4);
      float2 w2 = *(const float2*)(r1 + 8);
      Kr1v[0] = make_float2(w0.x, w0.y); Kr1v[1] = make_float2(w0.z, w0.w);
      Kr1v[2] = make_float2(w1.x, w1.y); Kr1v[3] = make_float2(w1.z, w1.w);
      Kr1v[4] = w2;
    }

    // ---- Sinkhorn iters 1-2 in log domain ----
#pragma unroll 1
    for (int it = 0; it < 2; ++it) {
      float2 v[8]; float v16;
      if (it == 0) {
#pragma unroll
        for (int i = 0; i < 8; ++i) v[i] = Kc2v[i];
        v16 = k16;
      } else {
        float4 f0 = *(const float4*)&fL[wv][p][0];
        float4 f1 = *(const float4*)&fL[wv][p][4];
        float4 f2 = *(const float4*)&fL[wv][p][8];
        float4 f3 = *(const float4*)&fL[wv][p][12];
        float fx = fL[wv][p][16];
        v[0] = pk_add(Kc2v[0], make_float2(f0.x, f0.y));
        v[1] = pk_add(Kc2v[1], make_float2(f0.z, f0.w));
        v[2] = pk_add(Kc2v[2], make_float2(f1.x, f1.y));
        v[3] = pk_add(Kc2v[3], make_float2(f1.z, f1.w));
        v[4] = pk_add(Kc2v[4], make_float2(f2.x, f2.y));
        v[5] = pk_add(Kc2v[5], make_float2(f2.z, f2.w));
        v[6] = pk_add(Kc2v[6], make_float2(f3.x, f3.y));
        v[7] = pk_add(Kc2v[7], make_float2(f3.z, f3.w));
        v16 = k16 + fx;
      }
      float2 m01 = pk_max(pk_max(v[0], v[1]), pk_max(v[2], v[3]));
      float2 m23 = pk_max(pk_max(v[4], v[5]), pk_max(v[6], v[7]));
      float2 mm = pk_max(m01, m23);
      float mx = fmaxf(fmaxf(mm.x, mm.y), v16);
      float2 mxb = make_float2(mx, mx);
      float2 ssA = pk_exp2(pk_sub(v[0], mxb));
      ssA = pk_add(ssA, pk_exp2(pk_sub(v[1], mxb)));
      ssA = pk_add(ssA, pk_exp2(pk_sub(v[2], mxb)));
      ssA = pk_add(ssA, pk_exp2(pk_sub(v[3], mxb)));
      float2 ssB = pk_exp2(pk_sub(v[4], mxb));
      ssB = pk_add(ssB, pk_exp2(pk_sub(v[5], mxb)));
      ssB = pk_add(ssB, pk_exp2(pk_sub(v[6], mxb)));
      ssB = pk_add(ssB, pk_exp2(pk_sub(v[7], mxb)));
      float2 ss = pk_add(ssA, ssB);
      float s = ss.x + ss.y + EXP2F(v16 - mx);
      g2 = LOGQ2 - mx - LOG2F(s);
      if (act) gL[wv][p][b] = g2;
      CBAR();
      {
        float4 g0 = *(const float4*)&gL[wv][p][0];
        float4 g1 = *(const float4*)&gL[wv][p][4];
        float2 gx = *(const float2*)&gL[wv][p][8];
        gr[0] = make_float2(g0.x, g0.y); gr[1] = make_float2(g0.z, g0.w);
        gr[2] = make_float2(g1.x, g1.y); gr[3] = make_float2(g1.z, g1.w);
        gr[4] = gx;
      }
      float2 w0[5], w1[5];
#pragma unroll
      for (int j = 0; j < 5; ++j) w0[j] = pk_add(Kr0v[j], gr[j]);
#pragma unroll
      for (int j = 0; j < 5; ++j) w1[j] = pk_add(Kr1v[j], gr[j]);
      float2 a01 = pk_max(pk_max(w0[0], w0[1]), pk_max(w0[2], w0[3]));
      a01 = pk_max(a01, w0[4]);
      float mxa = fmaxf(a01.x, a01.y);
      float2 b01 = pk_max(pk_max(w1[0], w1[1]), pk_max(w1[2], w1[3]));
      b01 = pk_max(b01, w1[4]);
      float mxb2 = fmaxf(b01.x, b01.y);
      float2 mab = make_float2(mxa, mxa);
      float2 mbb = make_float2(mxb2, mxb2);
      float2 sx = pk_exp2(pk_sub(w0[0], mab));
      sx = pk_add(sx, pk_exp2(pk_sub(w0[1], mab)));
      sx = pk_add(sx, pk_exp2(pk_sub(w0[2], mab)));
      sx = pk_add(sx, pk_exp2(pk_sub(w0[3], mab)));
      sx = pk_add(sx, pk_exp2(pk_sub(w0[4], mab)));
      float2 sy = pk_exp2(pk_sub(w1[0], mbb));
      sy = pk_add(sy, pk_exp2(pk_sub(w1[1], mbb)));
      sy = pk_add(sy, pk_exp2(pk_sub(w1[2], mbb)));
      sy = pk_add(sy, pk_exp2(pk_sub(w1[3], mbb)));
      sy = pk_add(sy, pk_exp2(pk_sub(w1[4], mbb)));
      fr0 = lp2_r0 - mxa - LOG2F(sx.x + sx.y);
      fr1 = lp2_r1 - mxb2 - LOG2F(sy.x + sy.y);
      if (act) {
        fL[wv][p][b] = fr0;
        if (b < 7) fL[wv][p][10 + b] = fr1;
      }
      CBAR();
    }

    // ---- stabilized kernels from (f2, g2) snapshot; rows re-paired (j, 10+j) ----
    float2 Kcs2[10];        // .y = 0 for j>=7 (dummy rows 17..19)
    float P00, P01, Q0;
    float2 Krs01[10];
    {
      float4 F0 = *(const float4*)&fL[wv][p][0];
      float4 F1 = *(const float4*)&fL[wv][p][4];
      float4 F2 = *(const float4*)&fL[wv][p][8];
      float4 F3 = *(const float4*)&fL[wv][p][12];
      float f16v = fL[wv][p][16];
      float fs[K1];
      fs[0] = F0.x; fs[1] = F0.y; fs[2] = F0.z; fs[3] = F0.w;
      fs[4] = F1.x; fs[5] = F1.y; fs[6] = F1.z; fs[7] = F1.w;
      fs[8] = F2.x; fs[9] = F2.y; fs[10] = F2.z; fs[11] = F2.w;
      fs[12] = F3.x; fs[13] = F3.y; fs[14] = F3.z; fs[15] = F3.w;
      fs[16] = f16v;
      float qs[K1];
#pragma unroll
      for (int a = 0; a < K1; ++a) {
        float kcv = (a == 16) ? k16 : ((a & 1) ? Kc2v[a >> 1].y : Kc2v[a >> 1].x);
        qs[a] = kcv + fs[a];
      }
      float sigma = qs[0];
#pragma unroll
      for (int a = 1; a < K1; ++a) sigma = fmaxf(sigma, qs[a]);
#pragma unroll
      for (int j = 0; j < 10; ++j) {
        float kx = EXP2F(qs[j] - sigma);
        float ky = (j < 7) ? EXP2F(qs[10 + j] - sigma) : 0.f;
        Kcs2[j] = make_float2(kx, ky);
      }
      Q0 = EXP2F(clamp120(LOGQ2 - sigma - g2));
      float2 a0[5], a1[5];
#pragma unroll
      for (int j = 0; j < 5; ++j) a0[j] = pk_add(Kr0v[j], gr[j]);
#pragma unroll
      for (int j = 0; j < 5; ++j) a1[j] = pk_add(Kr1v[j], gr[j]);
      float2 r0m = pk_max(pk_max(a0[0], a0[1]), pk_max(a0[2], a0[3]));
      r0m = pk_max(r0m, a0[4]);
      float rho0 = fmaxf(r0m.x, r0m.y);
      float2 r1m = pk_max(pk_max(a1[0], a1[1]), pk_max(a1[2], a1[3]));
      r1m = pk_max(r1m, a1[4]);
      float rho1 = fmaxf(r1m.x, r1m.y);
#pragma unroll
      for (int j = 0; j < 5; ++j) {
        Krs01[2 * j]     = make_float2(EXP2F(a0[j].x - rho0), EXP2F(a1[j].x - rho1));
        Krs01[2 * j + 1] = make_float2(EXP2F(a0[j].y - rho0), EXP2F(a1[j].y - rho1));
      }
      P00 = EXP2F(clamp120((lp2_r0 - rho0) - fr0));
      P01 = EXP2F(clamp120((lp2_r1 - rho1) - fr1));
    }

    // ---- Sinkhorn iters 3..20: pure multiplicative, in-order DS exchanges ----
    float Slast, t0, t1;
    {  // peeled iter 3: u == 1
      float2 SA = pk_add(pk_add(Kcs2[0], Kcs2[1]), pk_add(Kcs2[2], Kcs2[3]));
      float2 SB = pk_add(pk_add(Kcs2[4], Kcs2[5]), pk_add(Kcs2[6], Kcs2[7]));
      float2 S2 = pk_add(pk_add(SA, SB), pk_add(Kcs2[8], Kcs2[9]));
      float S = fmaxf(S2.x + S2.y, TINYF);
      Slast = S;
      float wb = Q0 * RCPF(S);
      if (act) wL[wv][p][b] = wb;
      CBAR();
      float4 W0 = *(const float4*)&wL[wv][p][0];
      float4 W1 = *(const float4*)&wL[wv][p][4];
      float2 W2 = *(const float2*)&wL[wv][p][8];
      float2 tA = pk_mul(Krs01[0], make_float2(W0.x, W0.x));
      tA = pk_fma(Krs01[1], make_float2(W0.y, W0.y), tA);
      tA = pk_fma(Krs01[2], make_float2(W0.z, W0.z), tA);
      tA = pk_fma(Krs01[3], make_float2(W0.w, W0.w), tA);
      tA = pk_fma(Krs01[4], make_float2(W1.x, W1.x), tA);
      float2 tB = pk_mul(Krs01[5], make_float2(W1.y, W1.y));
      tB = pk_fma(Krs01[6], make_float2(W1.z, W1.z), tB);
      tB = pk_fma(Krs01[7], make_float2(W1.w, W1.w), tB);
      tB = pk_fma(Krs01[8], make_float2(W2.x, W2.x), tB);
      tB = pk_fma(Krs01[9], make_float2(W2.y, W2.y), tB);
      float2 t01 = pk_add(tA, tB);
      t0 = t01.x; t1 = t01.y;
    }
#pragma unroll 1
    for (int it = 0; it < 17; ++it) {   // iters 4..20
      float u0 = P00 * RCPF(fmaxf(t0, TINYF));
      float u1 = P01 * RCPF(fmaxf(t1, TINYF));
      if (act) *(float2*)&uL[wv][p][2 * b] = make_float2(u0, u1);   // ONE b64 write
      CBAR();
      float4 U0 = *(const float4*)&uL[wv][p][0];    // (u0,u10, u1,u11)
      float4 U1 = *(const float4*)&uL[wv][p][4];
      float4 U2 = *(const float4*)&uL[wv][p][8];
      float4 U3 = *(const float4*)&uL[wv][p][12];
      float4 U4 = *(const float4*)&uL[wv][p][16];
      float2 SA = pk_mul(Kcs2[0], make_float2(U0.x, U0.y));
      SA = pk_fma(Kcs2[1], make_float2(U0.z, U0.w), SA);
      SA = pk_fma(Kcs2[2], make_float2(U1.x, U1.y), SA);
      SA = pk_fma(Kcs2[3], make_float2(U1.z, U1.w), SA);
      SA = pk_fma(Kcs2[4], make_float2(U2.x, U2.y), SA);
      float2 SB = pk_mul(Kcs2[5], make_float2(U2.z, U2.w));
      SB = pk_fma(Kcs2[6], make_float2(U3.x, U3.y), SB);
      SB = pk_fma(Kcs2[7], make_float2(U3.z, U3.w), SB);
      SB = pk_fma(Kcs2[8], make_float2(U4.x, U4.y), SB);
      SB = pk_fma(Kcs2[9], make_float2(U4.z, U4.w), SB);
      float2 S2 = pk_add(SA, SB);
      float S = fmaxf(S2.x + S2.y, TINYF);
      Slast = S;
      float wb = Q0 * RCPF(S);
      if (act) wL[wv][p][b] = wb;
      CBAR();
      float4 W0 = *(const float4*)&wL[wv][p][0];
      float4 W1 = *(const float4*)&wL[wv][p][4];
      float2 W2 = *(const float2*)&wL[wv][p][8];
      float2 tA = pk_mul(Krs01[0], make_float2(W0.x, W0.x));
      tA = pk_fma(Krs01[1], make_float2(W0.y, W0.y), tA);
      tA = pk_fma(Krs01[2], make_float2(W0.z, W0.z), tA);
      tA = pk_fma(Krs01[3], make_float2(W0.w, W0.w), tA);
      tA = pk_fma(Krs01[4], make_float2(W1.x, W1.x), tA);
      float2 tB = pk_mul(Krs01[5], make_float2(W1.y, W1.y));
      tB = pk_fma(Krs01[6], make_float2(W1.z, W1.z), tB);
      tB = pk_fma(Krs01[7], make_float2(W1.w, W1.w), tB);
      tB = pk_fma(Krs01[8], make_float2(W2.x, W2.x), tB);
      tB = pk_fma(Krs01[9], make_float2(W2.y, W2.y), tB);
      float2 t01 = pk_add(tA, tB);
      t0 = t01.x; t1 = t01.y;
    }

    // ---- final u + FW transport update: Tn = u * Kcs * (0.1/Slast), pairing matches ----
    {
      float u0 = P00 * RCPF(fmaxf(t0, TINYF));
      float u1 = P01 * RCPF(fmaxf(t1, TINYF));
      if (act) *(float2*)&uL[wv][p][2 * b] = make_float2(u0, u1);
      CBAR();
      float4 U0 = *(const float4*)&uL[wv][p][0];
      float4 U1 = *(const float4*)&uL[wv][p][4];
      float4 U2 = *(const float4*)&uL[wv][p][8];
      float4 U3 = *(const float4*)&uL[wv][p][12];
      float4 U4 = *(const float4*)&uL[wv][p][16];
      const float gam = 2.f / ((float)k + 2.f);
      const float gs = gam * 0.1f * RCPF(Slast);
      const float om = 1.f - gam;
      const float2 omb = make_float2(om, om);
      const float2 gsb = make_float2(gs, gs);
      float2 uu[10];
      uu[0] = make_float2(U0.x, U0.y); uu[1] = make_float2(U0.z, U0.w);
      uu[2] = make_float2(U1.x, U1.y); uu[3] = make_float2(U1.z, U1.w);
      uu[4] = make_float2(U2.x, U2.y); uu[5] = make_float2(U2.z, U2.w);
      uu[6] = make_float2(U3.x, U3.y); uu[7] = make_float2(U3.z, U3.w);
      uu[8] = make_float2(U4.x, U4.y); uu[9] = make_float2(U4.z, U4.w);
#pragma unroll
      for (int j = 0; j < 10; ++j)
        Tp2[j] = pk_fma(omb, Tp2[j], pk_mul(gsb, pk_mul(Kcs2[j], uu[j])));
    }
  }
}

extern "C" void kernel_launch(void* const* d_in, const int* in_sizes, int n_in,
                              void* d_out, int out_size, void* d_ws, size_t ws_size,
                              hipStream_t stream) {
  const float* x    = (const float*)d_in[0];
  const int*   ei   = (const int*)d_in[1];
  const float* tmpl = (const float*)d_in[2];
  const float* tf   = (const float*)d_in[3];
  float* out = (float*)d_out;

  int* cnt  = (int*)d_ws;
  int* ebuf = cnt + NNODE;
  int* nbrs = ebuf + (size_t)NNODE * CAP;
  int* kcnt = nbrs + (size_t)NNODE * KNB;
  int* Sg   = kcnt + NNODE;
  float* dots = (float*)(Sg + (size_t)NNODE * K1);
  float* nxv  = dots + (size_t)NNODE * (NT * TN);
  float* nF2  = nxv + NNODE;
  float* Bq   = nF2 + NT * TN;

  hipMemsetAsync(cnt, 0, NNODE * sizeof(int), stream);
  k_prep<<<625 + (NNODE + 63) / 64, 256, 0, stream>>>(ei, cnt, ebuf, x, tf, tmpl,
                                                      dots, nxv, nF2, Bq);
  k_select<<<(NNODE + 255) / 256, 256, 0, stream>>>(ei, cnt, ebuf, nbrs, kcnt, Sg);
  k_main<<<NNODE, 128, 0, stream>>>(tmpl, kcnt, Sg, nbrs, dots, nxv, nF2, Bq, out);
}

// Round 11
// 559.472 us; speedup vs baseline: 1.1283x; 1.1283x over previous
//
#include <hip/hip_runtime.h>
#include <math.h>

#define NNODE 10000
#define NEDGE 160000
#define KNB   16
#define K1    17
#define NT    10
#define TN    10
#define DF    128
#define CAP   64
#define NEG_BIG (-1e9f)

#define LOGQ2      (-3.32192809489f)   /* log2(0.1) */
#define KB_SCALE   (-14.4269504089f)   /* -10*log2e  */
#define CR_SCALE   (28.8539008178f)    /* +20*log2e  */
#define G_SCALE    (-0.069314718056f)  /* -ln2/10    */
#define LN2        0.69314718056f
#define TINYF      1e-30f

#if defined(__has_builtin)
#if __has_builtin(__builtin_amdgcn_exp2f)
#define EXP2F(x) __builtin_amdgcn_exp2f(x)
#endif
#if __has_builtin(__builtin_amdgcn_rcpf)
#define RCPF(x) __builtin_amdgcn_rcpf(x)
#endif
#endif
#ifndef EXP2F
#define EXP2F(x) __expf((x) * LN2)
#endif
#ifndef RCPF
#define RCPF(x) (1.0f / (x))
#endif
#define LOG2F(x) __log2f(x)

// Compiler-only barrier: DS ops from one wave execute IN ORDER in the LDS
// pipeline; compiler still emits lgkmcnt(N) before VALU consumes read data.
#define CBAR() asm volatile("" ::: "memory")

__device__ __forceinline__ float2 pk_add(float2 a, float2 b) { return make_float2(a.x + b.x, a.y + b.y); }
__device__ __forceinline__ float2 pk_sub(float2 a, float2 b) { return make_float2(a.x - b.x, a.y - b.y); }
__device__ __forceinline__ float2 pk_mul(float2 a, float2 b) { return make_float2(a.x * b.x, a.y * b.y); }
__device__ __forceinline__ float2 pk_max(float2 a, float2 b) { return make_float2(fmaxf(a.x, b.x), fmaxf(a.y, b.y)); }
__device__ __forceinline__ float2 pk_fma(float2 a, float2 b, float2 c) { return make_float2(fmaf(a.x, b.x, c.x), fmaf(a.y, b.y, c.y)); }
__device__ __forceinline__ float2 pk_exp2(float2 a) { return make_float2(EXP2F(a.x), EXP2F(a.y)); }
__device__ __forceinline__ float clamp120(float x) { return fminf(120.f, fmaxf(-120.f, x)); }

__device__ __forceinline__ int detect_wide(const int* ei) {
  int z = 0;
#pragma unroll
  for (int i = 0; i < 32; ++i) z |= ei[2 * i + 1];
  return z == 0;
}

// ---------- fused: edge bucketing + feature dots (16-node tiles) + template stats ----------
__global__ void __launch_bounds__(256) k_prep(const int* __restrict__ ei,
                                              int* cnt, int* ebuf,
                                              const float* __restrict__ x,
                                              const float* __restrict__ tf,
                                              const float* __restrict__ tmpl,
                                              float* __restrict__ dots,
                                              float* __restrict__ nxv,
                                              float* __restrict__ nF2,
                                              float* __restrict__ Bq) {
  __shared__ float xs[16][DF];   // 8 KB
  const int tid = threadIdx.x;
  if (blockIdx.x < 625) {          // hist: 625*256 == NEDGE
    int e = blockIdx.x * 256 + tid;
    int wide = detect_wide(ei);
    int s = wide ? ei[2 * e] : ei[e];
    int pos = atomicAdd(&cnt[s], 1);
    if (pos < CAP) ebuf[s * CAP + pos] = e;   // node-major: wave-coalesced select reads
    return;
  }
  const int db = blockIdx.x - 625;
  if (db == 0 && tid < NT * TN) {  // template stats, once
    const float* fp = tf + (size_t)tid * DF;
    float s = 0.f;
    for (int d = 0; d < DF; ++d) { float v = fp[d]; s += v * v; }
    nF2[tid] = s;
    const float* cp = tmpl + (size_t)tid * TN;
    float s2 = 0.f;
    for (int c = 0; c < TN; ++c) { float v = cp[c]; s2 += v * v; }
    Bq[tid] = 0.1f * s2;
  }
  const int nb = db * 16;
  const int nvalid = (NNODE - nb) < 16 ? (NNODE - nb) : 16;
  {
    const float4* xg = (const float4*)(x + (size_t)nb * DF);
    float4* xl = (float4*)&xs[0][0];
    for (int i = tid; i < nvalid * (DF / 4); i += 256) xl[i] = xg[i];
  }
  __syncthreads();
  for (int o = tid; o < nvalid * (NT * TN); o += 256) {
    int n = o / (NT * TN);
    int tb = o - n * (NT * TN);
    const float4* fp = (const float4*)(tf + (size_t)tb * DF);
    const float4* xp = (const float4*)&xs[n][0];
    float s = 0.f;
#pragma unroll
    for (int d = 0; d < DF / 4; ++d) {
      float4 a = xp[d], f = fp[d];
      s += a.x * f.x + a.y * f.y + a.z * f.z + a.w * f.w;
    }
    dots[(size_t)(nb + n) * (NT * TN) + tb] = s;
  }
  if (tid < nvalid) {
    const float4* xp = (const float4*)&xs[tid][0];
    float s = 0.f;
#pragma unroll
    for (int d = 0; d < DF / 4; ++d) {
      float4 a = xp[d];
      s += a.x * a.x + a.y * a.y + a.z * a.z + a.w * a.w;
    }
    nxv[nb + tid] = s;
  }
}

// ---------- wave-per-node: bitonic-sort 64 bucket entries, keep 16 smallest ----------
__global__ void __launch_bounds__(256) k_select(const int* __restrict__ ei,
                                                const int* __restrict__ cnt,
                                                const int* __restrict__ ebuf,
                                                int* __restrict__ nbrs,
                                                int* __restrict__ kcnt,
                                                int* __restrict__ Sg) {
  const int wv = threadIdx.x >> 6;
  const int lane = threadIdx.x & 63;
  const int i = blockIdx.x * 4 + wv;
  if (i >= NNODE) return;
  const int wide = detect_wide(ei);
  int c = cnt[i]; c = c > CAP ? CAP : c;
  int v = (lane < c) ? ebuf[i * CAP + lane] : 0x7FFFFFFF;
  // bitonic sort ascending across the 64-lane wave
#pragma unroll
  for (int k = 2; k <= 64; k <<= 1) {
#pragma unroll
    for (int j = k >> 1; j > 0; j >>= 1) {
      int pv = __shfl_xor(v, j, 64);
      bool up = ((lane & k) == 0);
      bool lower = ((lane & j) == 0);
      int mn = v < pv ? v : pv;
      int mx = v < pv ? pv : v;
      v = (lower == up) ? mn : mx;
    }
  }
  const int m = c < KNB ? c : KNB;
  if (lane == 0) { kcnt[i] = m; Sg[i * K1] = i; }
  if (lane < KNB) {
    int d = 0;
    if (lane < m) d = wide ? ei[2 * (NEDGE + v)] : ei[NEDGE + v];
    nbrs[i * KNB + lane] = d;
    Sg[i * K1 + 1 + lane] = d;
  }
}

// ---------- C1 bitmasks: one thread per (node, row) ----------
__global__ void __launch_bounds__(256) k_c1b(const int* __restrict__ nbrs,
                                             const int* __restrict__ kcnt,
                                             const int* __restrict__ Sg,
                                             unsigned int* __restrict__ bitsG,
                                             float* __restrict__ Ag) {
  int idx = blockIdx.x * 256 + threadIdx.x;
  if (idx >= NNODE * K1) return;
  int i = idx / K1;
  int a = idx - i * K1;
  int kc = kcnt[i];
  unsigned int vmask = (kc >= KNB) ? 0x1FFFFu : ((2u << kc) - 1u);
  unsigned int bits = 0;
  bool va = (a == 0) || (a - 1 < kc);
  if (va) {
    int S[K1];
#pragma unroll
    for (int b = 0; b < K1; ++b) S[b] = Sg[i * K1 + b];
    int u = S[a];
    int ku = kcnt[u];
    const int* np = nbrs + (size_t)u * KNB;
    for (int j = 0; j < ku; ++j) {
      int w = np[j];
#pragma unroll
      for (int b = 0; b < K1; ++b) bits |= (S[b] == w) ? (1u << b) : 0u;
    }
    bits &= vmask;
  }
  bitsG[idx] = bits;
  Ag[idx] = (float)__popc(bits) / (float)(1 + kc);
}

// ---------- FGW main: block = node, 2 waves x 5 pairs, lane = (pair, column) ----------
__global__ void __launch_bounds__(128, 3) k_main(
    const float* __restrict__ tmpl,
    const int* __restrict__ kcnt, const int* __restrict__ Sg,
    const unsigned int* __restrict__ bitsG, const float* __restrict__ Ag,
    const float* __restrict__ dots, const float* __restrict__ nxv,
    const float* __restrict__ nF2, const float* __restrict__ Bq,
    float* __restrict__ out)
{
  __shared__ float KT[2 * 5 * 204 + 48];  // pair stride 204 ≡ 12 mod 32; +48 pad for dummy rows
  __shared__ float fL[2][5][20];
  __shared__ float gL[2][5][12];
  __shared__ float uL[2][5][20];          // b64 pairs (u_j, u_{10+j})
  __shared__ float wL[2][5][12];
  __shared__ float accL[2][5][TN];

  const int wv = threadIdx.x >> 6;       // 0..1 = template half
  const int lane = threadIdx.x & 63;
  int p = lane / 10;
  const int b = lane - p * 10;
  const bool act = (p < 5);
  if (!act) p = 4;
  const int node = blockIdx.x;           // wave-uniform
  const int t = wv * 5 + p;
  const int tb = t * TN + b;
  float* KTp = &KT[(wv * 5 + p) * 204];

  const int kc = kcnt[node];
  const float cnt1 = (float)(1 + kc);
  const float inv_cnt1 = 1.f / cnt1;
  const float logp2v = -LOG2F(cnt1);
  const float lp2_r0 = ((b == 0) || (b - 1 < kc)) ? logp2v : NEG_BIG;  // row b
  const float lp2_r1 = ((9 + b) < kc) ? logp2v : NEG_BIG;              // row 10+b (b>=7: dummy)

  float2 c2v[5];
  {
    const float2* cp = (const float2*)(tmpl + (size_t)tb * TN);
#pragma unroll
    for (int j = 0; j < 5; ++j) c2v[j] = cp[j];
  }
  const float Bb = Bq[tb];
  const float nf2b = nF2[tb];

  float2 Kb2v[8]; float kb16;           // (2i,2i+1) pairing for log phase
  float2 Tp2[10];                       // (j, 10+j) pairing; .y=0 for j>=7 (dummy rows)
#pragma unroll
  for (int j = 0; j < 10; ++j) Tp2[j] = make_float2(0.f, 0.f);
  unsigned int bw[K1];
#pragma unroll
  for (int a = 0; a < K1; ++a) {
    bool va = (a == 0) || (a - 1 < kc);
    int sa = Sg[node * K1 + a];
    float Ma = (va ? (nxv[sa] - 2.f * dots[(size_t)sa * (NT * TN) + tb]) : 0.f) + nf2b;
    float base = 0.5f * Ma + Ag[node * K1 + a] + Bb;
    float kv = KB_SCALE * base;
    float tv = va ? (inv_cnt1 * 0.1f) : 0.f;
    if (a == 16) kb16 = kv;
    else if (a & 1) Kb2v[a >> 1].y = kv;
    else Kb2v[a >> 1].x = kv;
    if (a < 10) Tp2[a].x = tv; else Tp2[a - 10].y = tv;
    bw[a] = bitsG[node * K1 + a];
  }

  float2 Kc2v[8]; float k16 = 0.f;
  float2 Kr0v[5], Kr1v[5];
  float2 gr[5];
  float g2 = 0.f, fr0 = 0.f, fr1 = 0.f;

#pragma unroll 1
  for (int k = 0; k < 6; ++k) {
    // ---- stage Tp columns into KT (row-major, [a][b]) ----
    if (act) {
#pragma unroll
      for (int a = 0; a < K1; ++a)
        KTp[a * 12 + b] = (a < 10) ? Tp2[a].x : Tp2[a - 10].y;
    }
    CBAR();
    // ---- R = Tp @ C2^T (split chains) ----
    float R[K1];
#pragma unroll
    for (int c = 0; c < K1; ++c) {
      const float* row = &KTp[c * 12];
      float4 u0 = *(const float4*)row;
      float4 u1 = *(const float4*)(row + 4);
      float2 u2 = *(const float2*)(row + 8);
      float2 accA = pk_mul(make_float2(u0.x, u0.y), c2v[0]);
      accA = pk_fma(make_float2(u0.z, u0.w), c2v[1], accA);
      float2 accB = pk_mul(make_float2(u1.x, u1.y), c2v[2]);
      accB = pk_fma(make_float2(u1.z, u1.w), c2v[3], accB);
      accA = pk_fma(u2, c2v[4], accA);
      accA = pk_add(accA, accB);
      R[c] = accA.x + accA.y;
    }
    // ---- cross = C1 @ R via wave-uniform bitmasks → logK column ----
#pragma unroll
    for (int a = 0; a < K1; ++a) {
      float cr = 0.f;
      unsigned int m = bw[a];
      if (m) {
#pragma unroll
        for (int c = 0; c < K1; ++c)
          if (m & (1u << c)) cr += R[c];
      }
      float base = (a == 16) ? kb16 : ((a & 1) ? Kb2v[a >> 1].y : Kb2v[a >> 1].x);
      float val = base + CR_SCALE * cr;
      if (a == 16) k16 = val;
      else if (a & 1) Kc2v[a >> 1].y = val;
      else Kc2v[a >> 1].x = val;
    }

    if (k == 5) {  // final distance
      float acc = 0.f;
#pragma unroll
      for (int a = 0; a < K1; ++a) {
        bool va = (a == 0) || (a - 1 < kc);
        int sa = Sg[node * K1 + a];
        float Ma = (va ? (nxv[sa] - 2.f * dots[(size_t)sa * (NT * TN) + tb]) : 0.f) + nf2b;
        float kcv = (a == 16) ? k16 : ((a & 1) ? Kc2v[a >> 1].y : Kc2v[a >> 1].x);
        float tpv = (a < 10) ? Tp2[a].x : Tp2[a - 10].y;
        acc += tpv * (0.25f * Ma + 0.5f * (G_SCALE * kcv));
      }
      if (act) accL[wv][p][b] = acc;
      CBAR();
      if (lane < 5) {
        float s = 0.f;
#pragma unroll
        for (int j = 0; j < TN; ++j) s += accL[wv][lane][j];
        out[node * NT + wv * 5 + lane] = s;
      }
      return;
    }

    // ---- stage logK, read back rows b and 10+b ----
    CBAR();
    if (act) {
#pragma unroll
      for (int a = 0; a < 16; ++a) KTp[a * 12 + b] = (a & 1) ? Kc2v[a >> 1].y : Kc2v[a >> 1].x;
      KTp[16 * 12 + b] = k16;
    }
    CBAR();
    {
      const float* r0 = &KTp[b * 12];
      float4 u0 = *(const float4*)r0;
      float4 u1 = *(const float4*)(r0 + 4);
      float2 u2 = *(const float2*)(r0 + 8);
      Kr0v[0] = make_float2(u0.x, u0.y); Kr0v[1] = make_float2(u0.z, u0.w);
      Kr0v[2] = make_float2(u1.x, u1.y); Kr0v[3] = make_float2(u1.z, u1.w);
      Kr0v[4] = u2;
      const float* r1 = &KTp[(10 + b) * 12];  // b>=7: in-bounds junk (finite), row is dummy
      float4 w0 = *(const float4*)r1;
      float4 w1 = *(const float4*)(r1 + 4);
      float2 w2 = *(const float2*)(r1 + 8);
      Kr1v[0] = make_float2(w0.x, w0.y); Kr1v[1] = make_float2(w0.z, w0.w);
      Kr1v[2] = make_float2(w1.x, w1.y); Kr1v[3] = make_float2(w1.z, w1.w);
      Kr1v[4] = w2;
    }

    // ---- Sinkhorn iters 1-2 in log domain ----
#pragma unroll 1
    for (int it = 0; it < 2; ++it) {
      float2 v[8]; float v16;
      if (it == 0) {
#pragma unroll
        for (int i = 0; i < 8; ++i) v[i] = Kc2v[i];
        v16 = k16;
      } else {
        float4 f0 = *(const float4*)&fL[wv][p][0];
        float4 f1 = *(const float4*)&fL[wv][p][4];
        float4 f2 = *(const float4*)&fL[wv][p][8];
        float4 f3 = *(const float4*)&fL[wv][p][12];
        float fx = fL[wv][p][16];
        v[0] = pk_add(Kc2v[0], make_float2(f0.x, f0.y));
        v[1] = pk_add(Kc2v[1], make_float2(f0.z, f0.w));
        v[2] = pk_add(Kc2v[2], make_float2(f1.x, f1.y));
        v[3] = pk_add(Kc2v[3], make_float2(f1.z, f1.w));
        v[4] = pk_add(Kc2v[4], make_float2(f2.x, f2.y));
        v[5] = pk_add(Kc2v[5], make_float2(f2.z, f2.w));
        v[6] = pk_add(Kc2v[6], make_float2(f3.x, f3.y));
        v[7] = pk_add(Kc2v[7], make_float2(f3.z, f3.w));
        v16 = k16 + fx;
      }
      float2 m01 = pk_max(pk_max(v[0], v[1]), pk_max(v[2], v[3]));
      float2 m23 = pk_max(pk_max(v[4], v[5]), pk_max(v[6], v[7]));
      float2 mm = pk_max(m01, m23);
      float mx = fmaxf(fmaxf(mm.x, mm.y), v16);
      float2 mxb = make_float2(mx, mx);
      float2 ssA = pk_exp2(pk_sub(v[0], mxb));
      ssA = pk_add(ssA, pk_exp2(pk_sub(v[1], mxb)));
      ssA = pk_add(ssA, pk_exp2(pk_sub(v[2], mxb)));
      ssA = pk_add(ssA, pk_exp2(pk_sub(v[3], mxb)));
      float2 ssB = pk_exp2(pk_sub(v[4], mxb));
      ssB = pk_add(ssB, pk_exp2(pk_sub(v[5], mxb)));
      ssB = pk_add(ssB, pk_exp2(pk_sub(v[6], mxb)));
      ssB = pk_add(ssB, pk_exp2(pk_sub(v[7], mxb)));
      float2 ss = pk_add(ssA, ssB);
      float s = ss.x + ss.y + EXP2F(v16 - mx);
      g2 = LOGQ2 - mx - LOG2F(s);
      if (act) gL[wv][p][b] = g2;
      CBAR();
      {
        float4 g0 = *(const float4*)&gL[wv][p][0];
        float4 g1 = *(const float4*)&gL[wv][p][4];
        float2 gx = *(const float2*)&gL[wv][p][8];
        gr[0] = make_float2(g0.x, g0.y); gr[1] = make_float2(g0.z, g0.w);
        gr[2] = make_float2(g1.x, g1.y); gr[3] = make_float2(g1.z, g1.w);
        gr[4] = gx;
      }
      float2 w0[5], w1[5];
#pragma unroll
      for (int j = 0; j < 5; ++j) w0[j] = pk_add(Kr0v[j], gr[j]);
#pragma unroll
      for (int j = 0; j < 5; ++j) w1[j] = pk_add(Kr1v[j], gr[j]);
      float2 a01 = pk_max(pk_max(w0[0], w0[1]), pk_max(w0[2], w0[3]));
      a01 = pk_max(a01, w0[4]);
      float mxa = fmaxf(a01.x, a01.y);
      float2 b01 = pk_max(pk_max(w1[0], w1[1]), pk_max(w1[2], w1[3]));
      b01 = pk_max(b01, w1[4]);
      float mxb2 = fmaxf(b01.x, b01.y);
      float2 mab = make_float2(mxa, mxa);
      float2 mbb = make_float2(mxb2, mxb2);
      float2 sx = pk_exp2(pk_sub(w0[0], mab));
      sx = pk_add(sx, pk_exp2(pk_sub(w0[1], mab)));
      sx = pk_add(sx, pk_exp2(pk_sub(w0[2], mab)));
      sx = pk_add(sx, pk_exp2(pk_sub(w0[3], mab)));
      sx = pk_add(sx, pk_exp2(pk_sub(w0[4], mab)));
      float2 sy = pk_exp2(pk_sub(w1[0], mbb));
      sy = pk_add(sy, pk_exp2(pk_sub(w1[1], mbb)));
      sy = pk_add(sy, pk_exp2(pk_sub(w1[2], mbb)));
      sy = pk_add(sy, pk_exp2(pk_sub(w1[3], mbb)));
      sy = pk_add(sy, pk_exp2(pk_sub(w1[4], mbb)));
      fr0 = lp2_r0 - mxa - LOG2F(sx.x + sx.y);
      fr1 = lp2_r1 - mxb2 - LOG2F(sy.x + sy.y);
      if (act) {
        fL[wv][p][b] = fr0;
        if (b < 7) fL[wv][p][10 + b] = fr1;
      }
      CBAR();
    }

    // ---- stabilized kernels from (f2, g2) snapshot; rows re-paired (j, 10+j) ----
    float2 Kcs2[10];        // .y = 0 for j>=7 (dummy rows 17..19)
    float P00, P01, Q0;
    float2 Krs01[10];
    {
      float4 F0 = *(const float4*)&fL[wv][p][0];
      float4 F1 = *(const float4*)&fL[wv][p][4];
      float4 F2 = *(const float4*)&fL[wv][p][8];
      float4 F3 = *(const float4*)&fL[wv][p][12];
      float f16v = fL[wv][p][16];
      float fs[K1];
      fs[0] = F0.x; fs[1] = F0.y; fs[2] = F0.z; fs[3] = F0.w;
      fs[4] = F1.x; fs[5] = F1.y; fs[6] = F1.z; fs[7] = F1.w;
      fs[8] = F2.x; fs[9] = F2.y; fs[10] = F2.z; fs[11] = F2.w;
      fs[12] = F3.x; fs[13] = F3.y; fs[14] = F3.z; fs[15] = F3.w;
      fs[16] = f16v;
      float qs[K1];
#pragma unroll
      for (int a = 0; a < K1; ++a) {
        float kcv = (a == 16) ? k16 : ((a & 1) ? Kc2v[a >> 1].y : Kc2v[a >> 1].x);
        qs[a] = kcv + fs[a];
      }
      float sigma = qs[0];
#pragma unroll
      for (int a = 1; a < K1; ++a) sigma = fmaxf(sigma, qs[a]);
#pragma unroll
      for (int j = 0; j < 10; ++j) {
        float kx = EXP2F(qs[j] - sigma);
        float ky = (j < 7) ? EXP2F(qs[10 + j] - sigma) : 0.f;
        Kcs2[j] = make_float2(kx, ky);
      }
      Q0 = EXP2F(clamp120(LOGQ2 - sigma - g2));
      float2 a0[5], a1[5];
#pragma unroll
      for (int j = 0; j < 5; ++j) a0[j] = pk_add(Kr0v[j], gr[j]);
#pragma unroll
      for (int j = 0; j < 5; ++j) a1[j] = pk_add(Kr1v[j], gr[j]);
      float2 r0m = pk_max(pk_max(a0[0], a0[1]), pk_max(a0[2], a0[3]));
      r0m = pk_max(r0m, a0[4]);
      float rho0 = fmaxf(r0m.x, r0m.y);
      float2 r1m = pk_max(pk_max(a1[0], a1[1]), pk_max(a1[2], a1[3]));
      r1m = pk_max(r1m, a1[4]);
      float rho1 = fmaxf(r1m.x, r1m.y);
#pragma unroll
      for (int j = 0; j < 5; ++j) {
        Krs01[2 * j]     = make_float2(EXP2F(a0[j].x - rho0), EXP2F(a1[j].x - rho1));
        Krs01[2 * j + 1] = make_float2(EXP2F(a0[j].y - rho0), EXP2F(a1[j].y - rho1));
      }
      P00 = EXP2F(clamp120((lp2_r0 - rho0) - fr0));
      P01 = EXP2F(clamp120((lp2_r1 - rho1) - fr1));
    }

    // ---- Sinkhorn iters 3..20: pure multiplicative, in-order DS exchanges ----
    float Slast, t0, t1;
    {  // peeled iter 3: u == 1
      float2 SA = pk_add(pk_add(Kcs2[0], Kcs2[1]), pk_add(Kcs2[2], Kcs2[3]));
      float2 SB = pk_add(pk_add(Kcs2[4], Kcs2[5]), pk_add(Kcs2[6], Kcs2[7]));
      float2 S2 = pk_add(pk_add(SA, SB), pk_add(Kcs2[8], Kcs2[9]));
      float S = fmaxf(S2.x + S2.y, TINYF);
      Slast = S;
      float wb = Q0 * RCPF(S);
      if (act) wL[wv][p][b] = wb;
      CBAR();
      float4 W0 = *(const float4*)&wL[wv][p][0];
      float4 W1 = *(const float4*)&wL[wv][p][4];
      float2 W2 = *(const float2*)&wL[wv][p][8];
      float2 tA = pk_mul(Krs01[0], make_float2(W0.x, W0.x));
      tA = pk_fma(Krs01[1], make_float2(W0.y, W0.y), tA);
      tA = pk_fma(Krs01[2], make_float2(W0.z, W0.z), tA);
      tA = pk_fma(Krs01[3], make_float2(W0.w, W0.w), tA);
      tA = pk_fma(Krs01[4], make_float2(W1.x, W1.x), tA);
      float2 tB = pk_mul(Krs01[5], make_float2(W1.y, W1.y));
      tB = pk_fma(Krs01[6], make_float2(W1.z, W1.z), tB);
      tB = pk_fma(Krs01[7], make_float2(W1.w, W1.w), tB);
      tB = pk_fma(Krs01[8], make_float2(W2.x, W2.x), tB);
      tB = pk_fma(Krs01[9], make_float2(W2.y, W2.y), tB);
      float2 t01 = pk_add(tA, tB);
      t0 = t01.x; t1 = t01.y;
    }
#pragma unroll 1
    for (int it = 0; it < 17; ++it) {   // iters 4..20
      float u0 = P00 * RCPF(fmaxf(t0, TINYF));
      float u1 = P01 * RCPF(fmaxf(t1, TINYF));
      if (act) *(float2*)&uL[wv][p][2 * b] = make_float2(u0, u1);   // ONE b64 write
      CBAR();
      float4 U0 = *(const float4*)&uL[wv][p][0];    // (u0,u10, u1,u11)
      float4 U1 = *(const float4*)&uL[wv][p][4];
      float4 U2 = *(const float4*)&uL[wv][p][8];
      float4 U3 = *(const float4*)&uL[wv][p][12];
      float4 U4 = *(const float4*)&uL[wv][p][16];
      float2 SA = pk_mul(Kcs2[0], make_float2(U0.x, U0.y));
      SA = pk_fma(Kcs2[1], make_float2(U0.z, U0.w), SA);
      SA = pk_fma(Kcs2[2], make_float2(U1.x, U1.y), SA);
      SA = pk_fma(Kcs2[3], make_float2(U1.z, U1.w), SA);
      SA = pk_fma(Kcs2[4], make_float2(U2.x, U2.y), SA);
      float2 SB = pk_mul(Kcs2[5], make_float2(U2.z, U2.w));
      SB = pk_fma(Kcs2[6], make_float2(U3.x, U3.y), SB);
      SB = pk_fma(Kcs2[7], make_float2(U3.z, U3.w), SB);
      SB = pk_fma(Kcs2[8], make_float2(U4.x, U4.y), SB);
      SB = pk_fma(Kcs2[9], make_float2(U4.z, U4.w), SB);
      float2 S2 = pk_add(SA, SB);
      float S = fmaxf(S2.x + S2.y, TINYF);
      Slast = S;
      float wb = Q0 * RCPF(S);
      if (act) wL[wv][p][b] = wb;
      CBAR();
      float4 W0 = *(const float4*)&wL[wv][p][0];
      float4 W1 = *(const float4*)&wL[wv][p][4];
      float2 W2 = *(const float2*)&wL[wv][p][8];
      float2 tA = pk_mul(Krs01[0], make_float2(W0.x, W0.x));
      tA = pk_fma(Krs01[1], make_float2(W0.y, W0.y), tA);
      tA = pk_fma(Krs01[2], make_float2(W0.z, W0.z), tA);
      tA = pk_fma(Krs01[3], make_float2(W0.w, W0.w), tA);
      tA = pk_fma(Krs01[4], make_float2(W1.x, W1.x), tA);
      float2 tB = pk_mul(Krs01[5], make_float2(W1.y, W1.y));
      tB = pk_fma(Krs01[6], make_float2(W1.z, W1.z), tB);
      tB = pk_fma(Krs01[7], make_float2(W1.w, W1.w), tB);
      tB = pk_fma(Krs01[8], make_float2(W2.x, W2.x), tB);
      tB = pk_fma(Krs01[9], make_float2(W2.y, W2.y), tB);
      float2 t01 = pk_add(tA, tB);
      t0 = t01.x; t1 = t01.y;
    }

    // ---- final u + FW transport update: Tn = u * Kcs * (0.1/Slast), pairing matches ----
    {
      float u0 = P00 * RCPF(fmaxf(t0, TINYF));
      float u1 = P01 * RCPF(fmaxf(t1, TINYF));
      if (act) *(float2*)&uL[wv][p][2 * b] = make_float2(u0, u1);
      CBAR();
      float4 U0 = *(const float4*)&uL[wv][p][0];
      float4 U1 = *(const float4*)&uL[wv][p][4];
      float4 U2 = *(const float4*)&uL[wv][p][8];
      float4 U3 = *(const float4*)&uL[wv][p][12];
      float4 U4 = *(const float4*)&uL[wv][p][16];
      const float gam = 2.f / ((float)k + 2.f);
      const float gs = gam * 0.1f * RCPF(Slast);
      const float om = 1.f - gam;
      const float2 omb = make_float2(om, om);
      const float2 gsb = make_float2(gs, gs);
      float2 uu[10];
      uu[0] = make_float2(U0.x, U0.y); uu[1] = make_float2(U0.z, U0.w);
      uu[2] = make_float2(U1.x, U1.y); uu[3] = make_float2(U1.z, U1.w);
      uu[4] = make_float2(U2.x, U2.y); uu[5] = make_float2(U2.z, U2.w);
      uu[6] = make_float2(U3.x, U3.y); uu[7] = make_float2(U3.z, U3.w);
      uu[8] = make_float2(U4.x, U4.y); uu[9] = make_float2(U4.z, U4.w);
#pragma unroll
      for (int j = 0; j < 10; ++j)
        Tp2[j] = pk_fma(omb, Tp2[j], pk_mul(gsb, pk_mul(Kcs2[j], uu[j])));
    }
  }
}

extern "C" void kernel_launch(void* const* d_in, const int* in_sizes, int n_in,
                              void* d_out, int out_size, void* d_ws, size_t ws_size,
                              hipStream_t stream) {
  const float* x    = (const float*)d_in[0];
  const int*   ei   = (const int*)d_in[1];
  const float* tmpl = (const float*)d_in[2];
  const float* tf   = (const float*)d_in[3];
  float* out = (float*)d_out;

  int* cnt  = (int*)d_ws;
  int* ebuf = cnt + NNODE;
  int* nbrs = ebuf + (size_t)NNODE * CAP;
  int* kcnt = nbrs + (size_t)NNODE * KNB;
  int* Sg   = kcnt + NNODE;
  unsigned int* bits = (unsigned int*)(Sg + (size_t)NNODE * K1);
  float* Ag   = (float*)(bits + (size_t)NNODE * K1);
  float* dots = Ag + (size_t)NNODE * K1;
  float* nxv  = dots + (size_t)NNODE * (NT * TN);
  float* nF2  = nxv + NNODE;
  float* Bq   = nF2 + NT * TN;

  hipMemsetAsync(cnt, 0, NNODE * sizeof(int), stream);
  k_prep<<<625 + (NNODE + 15) / 16, 256, 0, stream>>>(ei, cnt, ebuf, x, tf, tmpl,
                                                      dots, nxv, nF2, Bq);
  k_select<<<(NNODE + 3) / 4, 256, 0, stream>>>(ei, cnt, ebuf, nbrs, kcnt, Sg);
  k_c1b<<<(NNODE * K1 + 255) / 256, 256, 0, stream>>>(nbrs, kcnt, Sg, bits, Ag);
  k_main<<<NNODE, 128, 0, stream>>>(tmpl, kcnt, Sg, bits, Ag, dots, nxv, nF2, Bq, out);
}

// Round 12
// 549.578 us; speedup vs baseline: 1.1487x; 1.0180x over previous
//
#include <hip/hip_runtime.h>
#include <math.h>

#define NNODE 10000
#define NEDGE 160000
#define KNB   16
#define K1    17
#define NT    10
#define TN    10
#define DF    128
#define CAP   64
#define NEG_BIG (-1e9f)

#define LOGQ2      (-3.32192809489f)   /* log2(0.1) */
#define KB_SCALE   (-14.4269504089f)   /* -10*log2e  */
#define CR_SCALE   (28.8539008178f)    /* +20*log2e  */
#define G_SCALE    (-0.069314718056f)  /* -ln2/10    */
#define LN2        0.69314718056f
#define TINYF      1e-30f

#if defined(__has_builtin)
#if __has_builtin(__builtin_amdgcn_exp2f)
#define EXP2F(x) __builtin_amdgcn_exp2f(x)
#endif
#if __has_builtin(__builtin_amdgcn_rcpf)
#define RCPF(x) __builtin_amdgcn_rcpf(x)
#endif
#endif
#ifndef EXP2F
#define EXP2F(x) __expf((x) * LN2)
#endif
#ifndef RCPF
#define RCPF(x) (1.0f / (x))
#endif
#define LOG2F(x) __log2f(x)

// Compiler-only barrier: DS ops from one wave execute IN ORDER in the LDS
// pipeline; compiler still emits lgkmcnt(N) before VALU consumes read data.
#define CBAR() asm volatile("" ::: "memory")

__device__ __forceinline__ float2 pk_add(float2 a, float2 b) { return make_float2(a.x + b.x, a.y + b.y); }
__device__ __forceinline__ float2 pk_sub(float2 a, float2 b) { return make_float2(a.x - b.x, a.y - b.y); }
__device__ __forceinline__ float2 pk_mul(float2 a, float2 b) { return make_float2(a.x * b.x, a.y * b.y); }
__device__ __forceinline__ float2 pk_max(float2 a, float2 b) { return make_float2(fmaxf(a.x, b.x), fmaxf(a.y, b.y)); }
__device__ __forceinline__ float2 pk_fma(float2 a, float2 b, float2 c) { return make_float2(fmaf(a.x, b.x, c.x), fmaf(a.y, b.y, c.y)); }
__device__ __forceinline__ float2 pk_exp2(float2 a) { return make_float2(EXP2F(a.x), EXP2F(a.y)); }
__device__ __forceinline__ float clamp120(float x) { return fminf(120.f, fmaxf(-120.f, x)); }

__device__ __forceinline__ int detect_wide(const int* ei) {
  int z = 0;
#pragma unroll
  for (int i = 0; i < 32; ++i) z |= ei[2 * i + 1];
  return z == 0;
}

// ---------- fused: edge bucketing + feature dots (16-node tiles) + template stats ----------
__global__ void __launch_bounds__(256) k_prep(const int* __restrict__ ei,
                                              int* cnt, int* ebuf,
                                              const float* __restrict__ x,
                                              const float* __restrict__ tf,
                                              const float* __restrict__ tmpl,
                                              float* __restrict__ dots,
                                              float* __restrict__ nxv,
                                              float* __restrict__ nF2,
                                              float* __restrict__ Bq) {
  __shared__ float xs[16][DF];   // 8 KB
  const int tid = threadIdx.x;
  if (blockIdx.x < 625) {          // hist: 625*256 == NEDGE
    int e = blockIdx.x * 256 + tid;
    int wide = detect_wide(ei);
    int s = wide ? ei[2 * e] : ei[e];
    int pos = atomicAdd(&cnt[s], 1);
    if (pos < CAP) ebuf[s * CAP + pos] = e;   // node-major: wave-coalesced select reads
    return;
  }
  const int db = blockIdx.x - 625;
  if (db == 0 && tid < NT * TN) {  // template stats, once
    const float* fp = tf + (size_t)tid * DF;
    float s = 0.f;
    for (int d = 0; d < DF; ++d) { float v = fp[d]; s += v * v; }
    nF2[tid] = s;
    const float* cp = tmpl + (size_t)tid * TN;
    float s2 = 0.f;
    for (int c = 0; c < TN; ++c) { float v = cp[c]; s2 += v * v; }
    Bq[tid] = 0.1f * s2;
  }
  const int nb = db * 16;
  const int nvalid = (NNODE - nb) < 16 ? (NNODE - nb) : 16;
  {
    const float4* xg = (const float4*)(x + (size_t)nb * DF);
    float4* xl = (float4*)&xs[0][0];
    for (int i = tid; i < nvalid * (DF / 4); i += 256) xl[i] = xg[i];
  }
  __syncthreads();
  for (int o = tid; o < nvalid * (NT * TN); o += 256) {
    int n = o / (NT * TN);
    int tb = o - n * (NT * TN);
    const float4* fp = (const float4*)(tf + (size_t)tb * DF);
    const float4* xp = (const float4*)&xs[n][0];
    float s = 0.f;
#pragma unroll
    for (int d = 0; d < DF / 4; ++d) {
      float4 a = xp[d], f = fp[d];
      s += a.x * f.x + a.y * f.y + a.z * f.z + a.w * f.w;
    }
    dots[(size_t)(nb + n) * (NT * TN) + tb] = s;
  }
  if (tid < nvalid) {
    const float4* xp = (const float4*)&xs[tid][0];
    float s = 0.f;
#pragma unroll
    for (int d = 0; d < DF / 4; ++d) {
      float4 a = xp[d];
      s += a.x * a.x + a.y * a.y + a.z * a.z + a.w * a.w;
    }
    nxv[nb + tid] = s;
  }
}

// ---------- wave-per-node: bitonic-sort 64 bucket entries, keep 16 smallest ----------
__global__ void __launch_bounds__(256) k_select(const int* __restrict__ ei,
                                                const int* __restrict__ cnt,
                                                const int* __restrict__ ebuf,
                                                int* __restrict__ nbrs,
                                                int* __restrict__ kcnt,
                                                int* __restrict__ Sg) {
  const int wv = threadIdx.x >> 6;
  const int lane = threadIdx.x & 63;
  const int i = blockIdx.x * 4 + wv;
  if (i >= NNODE) return;
  const int wide = detect_wide(ei);
  int c = cnt[i]; c = c > CAP ? CAP : c;
  int v = (lane < c) ? ebuf[i * CAP + lane] : 0x7FFFFFFF;
#pragma unroll
  for (int k = 2; k <= 64; k <<= 1) {
#pragma unroll
    for (int j = k >> 1; j > 0; j >>= 1) {
      int pv = __shfl_xor(v, j, 64);
      bool up = ((lane & k) == 0);
      bool lower = ((lane & j) == 0);
      int mn = v < pv ? v : pv;
      int mx = v < pv ? pv : v;
      v = (lower == up) ? mn : mx;
    }
  }
  const int m = c < KNB ? c : KNB;
  if (lane == 0) { kcnt[i] = m; Sg[i * K1] = i; }
  if (lane < KNB) {
    int d = 0;
    if (lane < m) d = wide ? ei[2 * (NEDGE + v)] : ei[NEDGE + v];
    nbrs[i * KNB + lane] = d;
    Sg[i * K1 + 1 + lane] = d;
  }
}

// ---------- C1 bitmasks: one thread per (node, row) ----------
__global__ void __launch_bounds__(256) k_c1b(const int* __restrict__ nbrs,
                                             const int* __restrict__ kcnt,
                                             const int* __restrict__ Sg,
                                             unsigned int* __restrict__ bitsG,
                                             float* __restrict__ Ag) {
  int idx = blockIdx.x * 256 + threadIdx.x;
  if (idx >= NNODE * K1) return;
  int i = idx / K1;
  int a = idx - i * K1;
  int kc = kcnt[i];
  unsigned int vmask = (kc >= KNB) ? 0x1FFFFu : ((2u << kc) - 1u);
  unsigned int bits = 0;
  bool va = (a == 0) || (a - 1 < kc);
  if (va) {
    int S[K1];
#pragma unroll
    for (int b = 0; b < K1; ++b) S[b] = Sg[i * K1 + b];
    int u = S[a];
    int ku = kcnt[u];
    const int* np = nbrs + (size_t)u * KNB;
    for (int j = 0; j < ku; ++j) {
      int w = np[j];
#pragma unroll
      for (int b = 0; b < K1; ++b) bits |= (S[b] == w) ? (1u << b) : 0u;
    }
    bits &= vmask;
  }
  bitsG[idx] = bits;
  Ag[idx] = (float)__popc(bits) / (float)(1 + kc);
}

// ---------- FGW main: block = node, 2 waves x 5 pairs (+dummy slot 5), branch-free LDS ----------
__global__ void __launch_bounds__(128, 3) k_main(
    const float* __restrict__ tmpl,
    const int* __restrict__ kcnt, const int* __restrict__ Sg,
    const unsigned int* __restrict__ bitsG, const float* __restrict__ Ag,
    const float* __restrict__ dots, const float* __restrict__ nxv,
    const float* __restrict__ nF2, const float* __restrict__ Bq,
    float* __restrict__ out)
{
  __shared__ float KT[2 * 6 * 204 + 48];  // 6 slots/wave (slot 5 = dummy); stride 204 ≡ 12 mod 32
  __shared__ float fL[2][6][20];
  __shared__ float gL[2][6][12];
  __shared__ float uL[2][6][20];          // b64 pairs (u_j, u_{10+j})
  __shared__ float wL[2][6][20];          // DUPLICATED pairs (w_b, w_b) -> pk operands direct
  __shared__ float accL[2][6][TN];

  const int wv = threadIdx.x >> 6;       // 0..1 = template half
  const int lane = threadIdx.x & 63;
  const int p0 = lane / 10;
  const int b = lane - p0 * 10;
  const bool act = (p0 < 5);
  const int p = act ? p0 : 5;            // inactive lanes -> dummy LDS slot
  const int node = blockIdx.x;           // wave-uniform
  const int tb = act ? ((wv * 5 + p0) * TN + b) : 0;   // clamp: no OOB global reads
  float* KTp = &KT[(wv * 6 + p) * 204];

  const int kc = kcnt[node];
  const float cnt1 = (float)(1 + kc);
  const float inv_cnt1 = 1.f / cnt1;
  const float logp2v = -LOG2F(cnt1);
  const float lp2_r0 = ((b == 0) || (b - 1 < kc)) ? logp2v : NEG_BIG;  // row b
  const float lp2_r1 = ((9 + b) < kc) ? logp2v : NEG_BIG;              // row 10+b (b>=7: dummy)

  float2 c2v[5];
  {
    const float2* cp = (const float2*)(tmpl + (size_t)tb * TN);
#pragma unroll
    for (int j = 0; j < 5; ++j) c2v[j] = cp[j];
  }
  const float Bb = Bq[tb];
  const float nf2b = nF2[tb];

  float2 Kb2v[8]; float kb16;           // (2i,2i+1) pairing for log phase
  float2 Tp2[10];                       // (j, 10+j) pairing; .y=0 for j>=7 (dummy rows)
#pragma unroll
  for (int j = 0; j < 10; ++j) Tp2[j] = make_float2(0.f, 0.f);
  unsigned int bw[K1];
#pragma unroll
  for (int a = 0; a < K1; ++a) {
    bool va = (a == 0) || (a - 1 < kc);
    int sa = Sg[node * K1 + a];
    float Ma = (va ? (nxv[sa] - 2.f * dots[(size_t)sa * (NT * TN) + tb]) : 0.f) + nf2b;
    float base = 0.5f * Ma + Ag[node * K1 + a] + Bb;
    float kv = KB_SCALE * base;
    float tv = va ? (inv_cnt1 * 0.1f) : 0.f;
    if (a == 16) kb16 = kv;
    else if (a & 1) Kb2v[a >> 1].y = kv;
    else Kb2v[a >> 1].x = kv;
    if (a < 10) Tp2[a].x = tv; else Tp2[a - 10].y = tv;
    bw[a] = bitsG[node * K1 + a];
  }

  float2 Kc2v[8]; float k16 = 0.f;
  float2 Kr0v[5], Kr1v[5];
  float2 gr[5];
  float g2 = 0.f, fr0 = 0.f, fr1 = 0.f;

#pragma unroll 1
  for (int k = 0; k < 6; ++k) {
    // ---- stage Tp columns into KT (row-major, [a][b]) ----
#pragma unroll
    for (int a = 0; a < K1; ++a)
      KTp[a * 12 + b] = (a < 10) ? Tp2[a].x : Tp2[a - 10].y;
    CBAR();
    // ---- R = Tp @ C2^T (split chains) ----
    float R[K1];
#pragma unroll
    for (int c = 0; c < K1; ++c) {
      const float* row = &KTp[c * 12];
      float4 u0 = *(const float4*)row;
      float4 u1 = *(const float4*)(row + 4);
      float2 u2 = *(const float2*)(row + 8);
      float2 accA = pk_mul(make_float2(u0.x, u0.y), c2v[0]);
      accA = pk_fma(make_float2(u0.z, u0.w), c2v[1], accA);
      float2 accB = pk_mul(make_float2(u1.x, u1.y), c2v[2]);
      accB = pk_fma(make_float2(u1.z, u1.w), c2v[3], accB);
      accA = pk_fma(u2, c2v[4], accA);
      accA = pk_add(accA, accB);
      R[c] = accA.x + accA.y;
    }
    // ---- cross = C1 @ R via wave-uniform bitmasks → logK column ----
#pragma unroll
    for (int a = 0; a < K1; ++a) {
      float cr = 0.f;
      unsigned int m = bw[a];
      if (m) {
#pragma unroll
        for (int c = 0; c < K1; ++c)
          if (m & (1u << c)) cr += R[c];
      }
      float base = (a == 16) ? kb16 : ((a & 1) ? Kb2v[a >> 1].y : Kb2v[a >> 1].x);
      float val = base + CR_SCALE * cr;
      if (a == 16) k16 = val;
      else if (a & 1) Kc2v[a >> 1].y = val;
      else Kc2v[a >> 1].x = val;
    }

    if (k == 5) {  // final distance
      float acc = 0.f;
#pragma unroll
      for (int a = 0; a < K1; ++a) {
        bool va = (a == 0) || (a - 1 < kc);
        int sa = Sg[node * K1 + a];
        float Ma = (va ? (nxv[sa] - 2.f * dots[(size_t)sa * (NT * TN) + tb]) : 0.f) + nf2b;
        float kcv = (a == 16) ? k16 : ((a & 1) ? Kc2v[a >> 1].y : Kc2v[a >> 1].x);
        float tpv = (a < 10) ? Tp2[a].x : Tp2[a - 10].y;
        acc += tpv * (0.25f * Ma + 0.5f * (G_SCALE * kcv));
      }
      accL[wv][p][b] = acc;
      CBAR();
      if (lane < 5) {
        float s = 0.f;
#pragma unroll
        for (int j = 0; j < TN; ++j) s += accL[wv][lane][j];
        out[node * NT + wv * 5 + lane] = s;
      }
      return;
    }

    // ---- stage logK, read back rows b and 10+b ----
    CBAR();
#pragma unroll
    for (int a = 0; a < 16; ++a) KTp[a * 12 + b] = (a & 1) ? Kc2v[a >> 1].y : Kc2v[a >> 1].x;
    KTp[16 * 12 + b] = k16;
    CBAR();
    {
      const float* r0 = &KTp[b * 12];
      float4 u0 = *(const float4*)r0;
      float4 u1 = *(const float4*)(r0 + 4);
      float2 u2 = *(const float2*)(r0 + 8);
      Kr0v[0] = make_float2(u0.x, u0.y); Kr0v[1] = make_float2(u0.z, u0.w);
      Kr0v[2] = make_float2(u1.x, u1.y); Kr0v[3] = make_float2(u1.z, u1.w);
      Kr0v[4] = u2;
      const float* r1 = &KTp[(10 + b) * 12];  // b>=7: in-bounds junk (finite), row is dummy
      float4 w0 = *(const float4*)r1;
      float4 w1 = *(const float4*)(r1 + 4);
      float2 w2 = *(const float2*)(r1 + 8);
      Kr1v[0] = make_float2(w0.x, w0.y); Kr1v[1] = make_float2(w0.z, w0.w);
      Kr1v[2] = make_float2(w1.x, w1.y); Kr1v[3] = make_float2(w1.z, w1.w);
      Kr1v[4] = w2;
    }

    // ---- Sinkhorn iters 1-2 in log domain ----
#pragma unroll 1
    for (int it = 0; it < 2; ++it) {
      float2 v[8]; float v16;
      if (it == 0) {
#pragma unroll
        for (int i = 0; i < 8; ++i) v[i] = Kc2v[i];
        v16 = k16;
      } else {
        float4 f0 = *(const float4*)&fL[wv][p][0];
        float4 f1 = *(const float4*)&fL[wv][p][4];
        float4 f2 = *(const float4*)&fL[wv][p][8];
        float4 f3 = *(const float4*)&fL[wv][p][12];
        float fx = fL[wv][p][16];
        v[0] = pk_add(Kc2v[0], make_float2(f0.x, f0.y));
        v[1] = pk_add(Kc2v[1], make_float2(f0.z, f0.w));
        v[2] = pk_add(Kc2v[2], make_float2(f1.x, f1.y));
        v[3] = pk_add(Kc2v[3], make_float2(f1.z, f1.w));
        v[4] = pk_add(Kc2v[4], make_float2(f2.x, f2.y));
        v[5] = pk_add(Kc2v[5], make_float2(f2.z, f2.w));
        v[6] = pk_add(Kc2v[6], make_float2(f3.x, f3.y));
        v[7] = pk_add(Kc2v[7], make_float2(f3.z, f3.w));
        v16 = k16 + fx;
      }
      float2 m01 = pk_max(pk_max(v[0], v[1]), pk_max(v[2], v[3]));
      float2 m23 = pk_max(pk_max(v[4], v[5]), pk_max(v[6], v[7]));
      float2 mm = pk_max(m01, m23);
      float mx = fmaxf(fmaxf(mm.x, mm.y), v16);
      float2 mxb = make_float2(mx, mx);
      float2 ssA = pk_exp2(pk_sub(v[0], mxb));
      ssA = pk_add(ssA, pk_exp2(pk_sub(v[1], mxb)));
      ssA = pk_add(ssA, pk_exp2(pk_sub(v[2], mxb)));
      ssA = pk_add(ssA, pk_exp2(pk_sub(v[3], mxb)));
      float2 ssB = pk_exp2(pk_sub(v[4], mxb));
      ssB = pk_add(ssB, pk_exp2(pk_sub(v[5], mxb)));
      ssB = pk_add(ssB, pk_exp2(pk_sub(v[6], mxb)));
      ssB = pk_add(ssB, pk_exp2(pk_sub(v[7], mxb)));
      float2 ss = pk_add(ssA, ssB);
      float s = ss.x + ss.y + EXP2F(v16 - mx);
      g2 = LOGQ2 - mx - LOG2F(s);
      gL[wv][p][b] = g2;
      CBAR();
      {
        float4 g0 = *(const float4*)&gL[wv][p][0];
        float4 g1 = *(const float4*)&gL[wv][p][4];
        float2 gx = *(const float2*)&gL[wv][p][8];
        gr[0] = make_float2(g0.x, g0.y); gr[1] = make_float2(g0.z, g0.w);
        gr[2] = make_float2(g1.x, g1.y); gr[3] = make_float2(g1.z, g1.w);
        gr[4] = gx;
      }
      float2 w0[5], w1[5];
#pragma unroll
      for (int j = 0; j < 5; ++j) w0[j] = pk_add(Kr0v[j], gr[j]);
#pragma unroll
      for (int j = 0; j < 5; ++j) w1[j] = pk_add(Kr1v[j], gr[j]);
      float2 a01 = pk_max(pk_max(w0[0], w0[1]), pk_max(w0[2], w0[3]));
      a01 = pk_max(a01, w0[4]);
      float mxa = fmaxf(a01.x, a01.y);
      float2 b01 = pk_max(pk_max(w1[0], w1[1]), pk_max(w1[2], w1[3]));
      b01 = pk_max(b01, w1[4]);
      float mxb2 = fmaxf(b01.x, b01.y);
      float2 mab = make_float2(mxa, mxa);
      float2 mbb = make_float2(mxb2, mxb2);
      float2 sx = pk_exp2(pk_sub(w0[0], mab));
      sx = pk_add(sx, pk_exp2(pk_sub(w0[1], mab)));
      sx = pk_add(sx, pk_exp2(pk_sub(w0[2], mab)));
      sx = pk_add(sx, pk_exp2(pk_sub(w0[3], mab)));
      sx = pk_add(sx, pk_exp2(pk_sub(w0[4], mab)));
      float2 sy = pk_exp2(pk_sub(w1[0], mbb));
      sy = pk_add(sy, pk_exp2(pk_sub(w1[1], mbb)));
      sy = pk_add(sy, pk_exp2(pk_sub(w1[2], mbb)));
      sy = pk_add(sy, pk_exp2(pk_sub(w1[3], mbb)));
      sy = pk_add(sy, pk_exp2(pk_sub(w1[4], mbb)));
      fr0 = lp2_r0 - mxa - LOG2F(sx.x + sx.y);
      fr1 = lp2_r1 - mxb2 - LOG2F(sy.x + sy.y);
      fL[wv][p][b] = fr0;
      fL[wv][p][10 + b] = fr1;   // b>=7 -> slots 17..19, never consumed
      CBAR();
    }

    // ---- stabilized kernels from (f2, g2) snapshot; rows re-paired (j, 10+j) ----
    float2 Kcs2[10];        // .y = 0 for j>=7 (dummy rows 17..19)
    float P00, P01, Q0;
    float2 Krs01[10];
    {
      float4 F0 = *(const float4*)&fL[wv][p][0];
      float4 F1 = *(const float4*)&fL[wv][p][4];
      float4 F2 = *(const float4*)&fL[wv][p][8];
      float4 F3 = *(const float4*)&fL[wv][p][12];
      float f16v = fL[wv][p][16];
      float fs[K1];
      fs[0] = F0.x; fs[1] = F0.y; fs[2] = F0.z; fs[3] = F0.w;
      fs[4] = F1.x; fs[5] = F1.y; fs[6] = F1.z; fs[7] = F1.w;
      fs[8] = F2.x; fs[9] = F2.y; fs[10] = F2.z; fs[11] = F2.w;
      fs[12] = F3.x; fs[13] = F3.y; fs[14] = F3.z; fs[15] = F3.w;
      fs[16] = f16v;
      float qs[K1];
#pragma unroll
      for (int a = 0; a < K1; ++a) {
        float kcv = (a == 16) ? k16 : ((a & 1) ? Kc2v[a >> 1].y : Kc2v[a >> 1].x);
        qs[a] = kcv + fs[a];
      }
      float sigma = qs[0];
#pragma unroll
      for (int a = 1; a < K1; ++a) sigma = fmaxf(sigma, qs[a]);
#pragma unroll
      for (int j = 0; j < 10; ++j) {
        float kx = EXP2F(qs[j] - sigma);
        float ky = (j < 7) ? EXP2F(qs[10 + j] - sigma) : 0.f;
        Kcs2[j] = make_float2(kx, ky);
      }
      Q0 = EXP2F(clamp120(LOGQ2 - sigma - g2));
      float2 a0[5], a1[5];
#pragma unroll
      for (int j = 0; j < 5; ++j) a0[j] = pk_add(Kr0v[j], gr[j]);
#pragma unroll
      for (int j = 0; j < 5; ++j) a1[j] = pk_add(Kr1v[j], gr[j]);
      float2 r0m = pk_max(pk_max(a0[0], a0[1]), pk_max(a0[2], a0[3]));
      r0m = pk_max(r0m, a0[4]);
      float rho0 = fmaxf(r0m.x, r0m.y);
      float2 r1m = pk_max(pk_max(a1[0], a1[1]), pk_max(a1[2], a1[3]));
      r1m = pk_max(r1m, a1[4]);
      float rho1 = fmaxf(r1m.x, r1m.y);
#pragma unroll
      for (int j = 0; j < 5; ++j) {
        Krs01[2 * j]     = make_float2(EXP2F(a0[j].x - rho0), EXP2F(a1[j].x - rho1));
        Krs01[2 * j + 1] = make_float2(EXP2F(a0[j].y - rho0), EXP2F(a1[j].y - rho1));
      }
      P00 = EXP2F(clamp120((lp2_r0 - rho0) - fr0));
      P01 = EXP2F(clamp120((lp2_r1 - rho1) - fr1));
    }

    // ---- Sinkhorn iters 3..20: pure multiplicative, duplicated-w exchange ----
    float Slast, t0, t1;
    {  // peeled iter 3: u == 1
      float2 SA = pk_add(pk_add(Kcs2[0], Kcs2[1]), pk_add(Kcs2[2], Kcs2[3]));
      float2 SB = pk_add(pk_add(Kcs2[4], Kcs2[5]), pk_add(Kcs2[6], Kcs2[7]));
      float2 S2 = pk_add(pk_add(SA, SB), pk_add(Kcs2[8], Kcs2[9]));
      float S = fmaxf(S2.x + S2.y, TINYF);
      Slast = S;
      float wb = Q0 * RCPF(S);
      *(float2*)&wL[wv][p][2 * b] = make_float2(wb, wb);
      CBAR();
      float4 W0 = *(const float4*)&wL[wv][p][0];
      float4 W1 = *(const float4*)&wL[wv][p][4];
      float4 W2 = *(const float4*)&wL[wv][p][8];
      float4 W3 = *(const float4*)&wL[wv][p][12];
      float4 W4 = *(const float4*)&wL[wv][p][16];
      float2 tA = pk_mul(Krs01[0], make_float2(W0.x, W0.y));
      tA = pk_fma(Krs01[1], make_float2(W0.z, W0.w), tA);
      tA = pk_fma(Krs01[2], make_float2(W1.x, W1.y), tA);
      tA = pk_fma(Krs01[3], make_float2(W1.z, W1.w), tA);
      tA = pk_fma(Krs01[4], make_float2(W2.x, W2.y), tA);
      float2 tB = pk_mul(Krs01[5], make_float2(W2.z, W2.w));
      tB = pk_fma(Krs01[6], make_float2(W3.x, W3.y), tB);
      tB = pk_fma(Krs01[7], make_float2(W3.z, W3.w), tB);
      tB = pk_fma(Krs01[8], make_float2(W4.x, W4.y), tB);
      tB = pk_fma(Krs01[9], make_float2(W4.z, W4.w), tB);
      float2 t01 = pk_add(tA, tB);
      t0 = t01.x; t1 = t01.y;
    }
#pragma unroll 1
    for (int it = 0; it < 17; ++it) {   // iters 4..20
      float u0 = P00 * RCPF(fmaxf(t0, TINYF));
      float u1 = P01 * RCPF(fmaxf(t1, TINYF));
      *(float2*)&uL[wv][p][2 * b] = make_float2(u0, u1);   // ONE b64 write
      CBAR();
      float4 U0 = *(const float4*)&uL[wv][p][0];    // (u0,u10, u1,u11)
      float4 U1 = *(const float4*)&uL[wv][p][4];
      float4 U2 = *(const float4*)&uL[wv][p][8];
      float4 U3 = *(const float4*)&uL[wv][p][12];
      float4 U4 = *(const float4*)&uL[wv][p][16];
      float2 SA = pk_mul(Kcs2[0], make_float2(U0.x, U0.y));
      SA = pk_fma(Kcs2[1], make_float2(U0.z, U0.w), SA);
      SA = pk_fma(Kcs2[2], make_float2(U1.x, U1.y), SA);
      SA = pk_fma(Kcs2[3], make_float2(U1.z, U1.w), SA);
      SA = pk_fma(Kcs2[4], make_float2(U2.x, U2.y), SA);
      float2 SB = pk_mul(Kcs2[5], make_float2(U2.z, U2.w));
      SB = pk_fma(Kcs2[6], make_float2(U3.x, U3.y), SB);
      SB = pk_fma(Kcs2[7], make_float2(U3.z, U3.w), SB);
      SB = pk_fma(Kcs2[8], make_float2(U4.x, U4.y), SB);
      SB = pk_fma(Kcs2[9], make_float2(U4.z, U4.w), SB);
      float2 S2 = pk_add(SA, SB);
      float S = fmaxf(S2.x + S2.y, TINYF);
      Slast = S;
      float wb = Q0 * RCPF(S);
      *(float2*)&wL[wv][p][2 * b] = make_float2(wb, wb);
      CBAR();
      float4 W0 = *(const float4*)&wL[wv][p][0];
      float4 W1 = *(const float4*)&wL[wv][p][4];
      float4 W2 = *(const float4*)&wL[wv][p][8];
      float4 W3 = *(const float4*)&wL[wv][p][12];
      float4 W4 = *(const float4*)&wL[wv][p][16];
      float2 tA = pk_mul(Krs01[0], make_float2(W0.x, W0.y));
      tA = pk_fma(Krs01[1], make_float2(W0.z, W0.w), tA);
      tA = pk_fma(Krs01[2], make_float2(W1.x, W1.y), tA);
      tA = pk_fma(Krs01[3], make_float2(W1.z, W1.w), tA);
      tA = pk_fma(Krs01[4], make_float2(W2.x, W2.y), tA);
      float2 tB = pk_mul(Krs01[5], make_float2(W2.z, W2.w));
      tB = pk_fma(Krs01[6], make_float2(W3.x, W3.y), tB);
      tB = pk_fma(Krs01[7], make_float2(W3.z, W3.w), tB);
      tB = pk_fma(Krs01[8], make_float2(W4.x, W4.y), tB);
      tB = pk_fma(Krs01[9], make_float2(W4.z, W4.w), tB);
      float2 t01 = pk_add(tA, tB);
      t0 = t01.x; t1 = t01.y;
    }

    // ---- final u + FW transport update: Tn = u * Kcs * (0.1/Slast), pairing matches ----
    {
      float u0 = P00 * RCPF(fmaxf(t0, TINYF));
      float u1 = P01 * RCPF(fmaxf(t1, TINYF));
      *(float2*)&uL[wv][p][2 * b] = make_float2(u0, u1);
      CBAR();
      float4 U0 = *(const float4*)&uL[wv][p][0];
      float4 U1 = *(const float4*)&uL[wv][p][4];
      float4 U2 = *(const float4*)&uL[wv][p][8];
      float4 U3 = *(const float4*)&uL[wv][p][12];
      float4 U4 = *(const float4*)&uL[wv][p][16];
      const float gam = 2.f / ((float)k + 2.f);
      const float gs = gam * 0.1f * RCPF(Slast);
      const float om = 1.f - gam;
      const float2 omb = make_float2(om, om);
      const float2 gsb = make_float2(gs, gs);
      float2 uu[10];
      uu[0] = make_float2(U0.x, U0.y); uu[1] = make_float2(U0.z, U0.w);
      uu[2] = make_float2(U1.x, U1.y); uu[3] = make_float2(U1.z, U1.w);
      uu[4] = make_float2(U2.x, U2.y); uu[5] = make_float2(U2.z, U2.w);
      uu[6] = make_float2(U3.x, U3.y); uu[7] = make_float2(U3.z, U3.w);
      uu[8] = make_float2(U4.x, U4.y); uu[9] = make_float2(U4.z, U4.w);
#pragma unroll
      for (int j = 0; j < 10; ++j)
        Tp2[j] = pk_fma(omb, Tp2[j], pk_mul(gsb, pk_mul(Kcs2[j], uu[j])));
    }
  }
}

extern "C" void kernel_launch(void* const* d_in, const int* in_sizes, int n_in,
                              void* d_out, int out_size, void* d_ws, size_t ws_size,
                              hipStream_t stream) {
  const float* x    = (const float*)d_in[0];
  const int*   ei   = (const int*)d_in[1];
  const float* tmpl = (const float*)d_in[2];
  const float* tf   = (const float*)d_in[3];
  float* out = (float*)d_out;

  int* cnt  = (int*)d_ws;
  int* ebuf = cnt + NNODE;
  int* nbrs = ebuf + (size_t)NNODE * CAP;
  int* kcnt = nbrs + (size_t)NNODE * KNB;
  int* Sg   = kcnt + NNODE;
  unsigned int* bits = (unsigned int*)(Sg + (size_t)NNODE * K1);
  float* Ag   = (float*)(bits + (size_t)NNODE * K1);
  float* dots = Ag + (size_t)NNODE * K1;
  float* nxv  = dots + (size_t)NNODE * (NT * TN);
  float* nF2  = nxv + NNODE;
  float* Bq   = nF2 + NT * TN;

  hipMemsetAsync(cnt, 0, NNODE * sizeof(int), stream);
  k_prep<<<625 + (NNODE + 15) / 16, 256, 0, stream>>>(ei, cnt, ebuf, x, tf, tmpl,
                                                      dots, nxv, nF2, Bq);
  k_select<<<(NNODE + 3) / 4, 256, 0, stream>>>(ei, cnt, ebuf, nbrs, kcnt, Sg);
  k_c1b<<<(NNODE * K1 + 255) / 256, 256, 0, stream>>>(nbrs, kcnt, Sg, bits, Ag);
  k_main<<<NNODE, 128, 0, stream>>>(tmpl, kcnt, Sg, bits, Ag, dots, nxv, nF2, Bq, out);
}

// Round 13
// 548.426 us; speedup vs baseline: 1.1511x; 1.0021x over previous
//
#include <hip/hip_runtime.h>
#include <math.h>

#define NNODE 10000
#define NEDGE 160000
#define KNB   16
#define K1    17
#define NT    10
#define TN    10
#define DF    128
#define CAP   64
#define NEG_BIG (-1e9f)

#define LOGQ2      (-3.32192809489f)   /* log2(0.1) */
#define KB_SCALE   (-14.4269504089f)   /* -10*log2e  */
#define CR_SCALE   (28.8539008178f)    /* +20*log2e  */
#define G_SCALE    (-0.069314718056f)  /* -ln2/10    */
#define LN2        0.69314718056f
#define TINYF      1e-30f

#if defined(__has_builtin)
#if __has_builtin(__builtin_amdgcn_exp2f)
#define EXP2F(x) __builtin_amdgcn_exp2f(x)
#endif
#if __has_builtin(__builtin_amdgcn_rcpf)
#define RCPF(x) __builtin_amdgcn_rcpf(x)
#endif
#endif
#ifndef EXP2F
#define EXP2F(x) __expf((x) * LN2)
#endif
#ifndef RCPF
#define RCPF(x) (1.0f / (x))
#endif
#define LOG2F(x) __log2f(x)

// Compiler-only barrier: DS ops from one wave execute IN ORDER in the LDS
// pipeline; compiler still emits lgkmcnt(N) before VALU consumes read data.
#define CBAR() asm volatile("" ::: "memory")

__device__ __forceinline__ float2 pk_add(float2 a, float2 b) { return make_float2(a.x + b.x, a.y + b.y); }
__device__ __forceinline__ float2 pk_sub(float2 a, float2 b) { return make_float2(a.x - b.x, a.y - b.y); }
__device__ __forceinline__ float2 pk_mul(float2 a, float2 b) { return make_float2(a.x * b.x, a.y * b.y); }
__device__ __forceinline__ float2 pk_max(float2 a, float2 b) { return make_float2(fmaxf(a.x, b.x), fmaxf(a.y, b.y)); }
__device__ __forceinline__ float2 pk_fma(float2 a, float2 b, float2 c) { return make_float2(fmaf(a.x, b.x, c.x), fmaf(a.y, b.y, c.y)); }
__device__ __forceinline__ float2 pk_exp2(float2 a) { return make_float2(EXP2F(a.x), EXP2F(a.y)); }
__device__ __forceinline__ float clamp120(float x) { return fminf(120.f, fmaxf(-120.f, x)); }

// int64-vs-int32 sniff, computed by ONE lane and broadcast (was per-thread: ~25M redundant loads)
__device__ __forceinline__ int detect_wide_wave(const int* ei) {
  int z = 0;
  if ((threadIdx.x & 63) == 0) {
#pragma unroll
    for (int i = 0; i < 32; ++i) z |= ei[2 * i + 1];
  }
  z = __shfl(z, 0, 64);
  return z == 0;
}

// ---------- fused: edge bucketing + feature dots (16-node tiles) + template stats ----------
__global__ void __launch_bounds__(256) k_prep(const int* __restrict__ ei,
                                              int* cnt, int* ebuf,
                                              const float* __restrict__ x,
                                              const float* __restrict__ tf,
                                              const float* __restrict__ tmpl,
                                              float* __restrict__ dots,
                                              float* __restrict__ nxv,
                                              float* __restrict__ nF2,
                                              float* __restrict__ Bq) {
  __shared__ float xs[16][DF];   // 8 KB
  const int tid = threadIdx.x;
  if (blockIdx.x < 625) {          // hist: 625*256 == NEDGE
    int wide = detect_wide_wave(ei);
    int e = blockIdx.x * 256 + tid;
    int s = wide ? ei[2 * e] : ei[e];
    int pos = atomicAdd(&cnt[s], 1);
    if (pos < CAP) ebuf[s * CAP + pos] = e;   // node-major: wave-coalesced select reads
    return;
  }
  const int db = blockIdx.x - 625;
  if (db == 0 && tid < NT * TN) {  // template stats, once
    const float* fp = tf + (size_t)tid * DF;
    float s = 0.f;
    for (int d = 0; d < DF; ++d) { float v = fp[d]; s += v * v; }
    nF2[tid] = s;
    const float* cp = tmpl + (size_t)tid * TN;
    float s2 = 0.f;
    for (int c = 0; c < TN; ++c) { float v = cp[c]; s2 += v * v; }
    Bq[tid] = 0.1f * s2;
  }
  const int nb = db * 16;
  const int nvalid = (NNODE - nb) < 16 ? (NNODE - nb) : 16;
  {
    const float4* xg = (const float4*)(x + (size_t)nb * DF);
    float4* xl = (float4*)&xs[0][0];
    for (int i = tid; i < nvalid * (DF / 4); i += 256) xl[i] = xg[i];
  }
  __syncthreads();
  for (int o = tid; o < nvalid * (NT * TN); o += 256) {
    int n = o / (NT * TN);
    int tb = o - n * (NT * TN);
    const float4* fp = (const float4*)(tf + (size_t)tb * DF);
    const float4* xp = (const float4*)&xs[n][0];
    float s = 0.f;
#pragma unroll
    for (int d = 0; d < DF / 4; ++d) {
      float4 a = xp[d], f = fp[d];
      s += a.x * f.x + a.y * f.y + a.z * f.z + a.w * f.w;
    }
    dots[(size_t)(nb + n) * (NT * TN) + tb] = s;
  }
  if (tid < nvalid) {
    const float4* xp = (const float4*)&xs[tid][0];
    float s = 0.f;
#pragma unroll
    for (int d = 0; d < DF / 4; ++d) {
      float4 a = xp[d];
      s += a.x * a.x + a.y * a.y + a.z * a.z + a.w * a.w;
    }
    nxv[nb + tid] = s;
  }
}

// ---------- wave-per-node: bitonic-sort 64 bucket entries, keep 16 smallest ----------
__global__ void __launch_bounds__(256) k_select(const int* __restrict__ ei,
                                                const int* __restrict__ cnt,
                                                const int* __restrict__ ebuf,
                                                int* __restrict__ nbrs,
                                                int* __restrict__ kcnt,
                                                int* __restrict__ Sg) {
  const int wv = threadIdx.x >> 6;
  const int lane = threadIdx.x & 63;
  const int i = blockIdx.x * 4 + wv;
  if (i >= NNODE) return;
  const int wide = detect_wide_wave(ei);
  int c = cnt[i]; c = c > CAP ? CAP : c;
  int v = (lane < c) ? ebuf[i * CAP + lane] : 0x7FFFFFFF;
#pragma unroll
  for (int k = 2; k <= 64; k <<= 1) {
#pragma unroll
    for (int j = k >> 1; j > 0; j >>= 1) {
      int pv = __shfl_xor(v, j, 64);
      bool up = ((lane & k) == 0);
      bool lower = ((lane & j) == 0);
      int mn = v < pv ? v : pv;
      int mx = v < pv ? pv : v;
      v = (lower == up) ? mn : mx;
    }
  }
  const int m = c < KNB ? c : KNB;
  if (lane == 0) { kcnt[i] = m; Sg[i * K1] = i; }
  if (lane < KNB) {
    int d = 0;
    if (lane < m) d = wide ? ei[2 * (NEDGE + v)] : ei[NEDGE + v];
    nbrs[i * KNB + lane] = d;
    Sg[i * K1 + 1 + lane] = d;
  }
}

// ---------- C1 bitmasks: one thread per (node, row) ----------
__global__ void __launch_bounds__(256) k_c1b(const int* __restrict__ nbrs,
                                             const int* __restrict__ kcnt,
                                             const int* __restrict__ Sg,
                                             unsigned int* __restrict__ bitsG,
                                             float* __restrict__ Ag) {
  int idx = blockIdx.x * 256 + threadIdx.x;
  if (idx >= NNODE * K1) return;
  int i = idx / K1;
  int a = idx - i * K1;
  int kc = kcnt[i];
  unsigned int vmask = (kc >= KNB) ? 0x1FFFFu : ((2u << kc) - 1u);
  unsigned int bits = 0;
  bool va = (a == 0) || (a - 1 < kc);
  if (va) {
    int S[K1];
#pragma unroll
    for (int b = 0; b < K1; ++b) S[b] = Sg[i * K1 + b];
    int u = S[a];
    int ku = kcnt[u];
    const int* np = nbrs + (size_t)u * KNB;
    for (int j = 0; j < ku; ++j) {
      int w = np[j];
#pragma unroll
      for (int b = 0; b < K1; ++b) bits |= (S[b] == w) ? (1u << b) : 0u;
    }
    bits &= vmask;
  }
  bitsG[idx] = bits;
  Ag[idx] = (float)__popc(bits) / (float)(1 + kc);
}

// ---------- FGW main: block = node, 2 waves x 5 pairs (+dummy slot 5), branch-free LDS ----------
__global__ void __launch_bounds__(128, 3) k_main(
    const float* __restrict__ tmpl,
    const int* __restrict__ kcnt, const int* __restrict__ Sg,
    const unsigned int* __restrict__ bitsG, const float* __restrict__ Ag,
    const float* __restrict__ dots, const float* __restrict__ nxv,
    const float* __restrict__ nF2, const float* __restrict__ Bq,
    float* __restrict__ out)
{
  __shared__ float KT[2 * 6 * 204 + 48];  // 6 slots/wave (slot 5 = dummy); stride 204 ≡ 12 mod 32
  __shared__ float fL[2][6][20];
  __shared__ float gL[2][6][12];
  __shared__ float uL[2][6][20];          // b64 pairs (u_j, u_{10+j})
  __shared__ float wL[2][6][20];          // DUPLICATED pairs (w_b, w_b) -> pk operands direct
  __shared__ float accL[2][6][TN];

  const int wv = threadIdx.x >> 6;       // 0..1 = template half
  const int lane = threadIdx.x & 63;
  const int p0 = lane / 10;
  const int b = lane - p0 * 10;
  const bool act = (p0 < 5);
  const int p = act ? p0 : 5;            // inactive lanes -> dummy LDS slot
  const int node = blockIdx.x;           // wave-uniform
  const int tb = act ? ((wv * 5 + p0) * TN + b) : 0;   // clamp: no OOB global reads
  float* KTp = &KT[(wv * 6 + p) * 204];

  const int kc = kcnt[node];
  const float cnt1 = (float)(1 + kc);
  const float inv_cnt1 = 1.f / cnt1;
  const float logp2v = -LOG2F(cnt1);
  const float lp2_r0 = ((b == 0) || (b - 1 < kc)) ? logp2v : NEG_BIG;  // row b
  const float lp2_r1 = ((9 + b) < kc) ? logp2v : NEG_BIG;              // row 10+b (b>=7: dummy)

  float2 c2v[5];
  {
    const float2* cp = (const float2*)(tmpl + (size_t)tb * TN);
#pragma unroll
    for (int j = 0; j < 5; ++j) c2v[j] = cp[j];
  }
  const float Bb = Bq[tb];
  const float nf2b = nF2[tb];

  float2 Kb2v[8]; float kb16;           // (2i,2i+1) pairing for log phase
  float2 Tp2[10];                       // (j, 10+j) pairing; .y=0 for j>=7 (dummy rows)
#pragma unroll
  for (int j = 0; j < 10; ++j) Tp2[j] = make_float2(0.f, 0.f);
  unsigned int bw[K1];
#pragma unroll
  for (int a = 0; a < K1; ++a) {
    bool va = (a == 0) || (a - 1 < kc);
    int sa = Sg[node * K1 + a];
    float Ma = (va ? (nxv[sa] - 2.f * dots[(size_t)sa * (NT * TN) + tb]) : 0.f) + nf2b;
    float base = 0.5f * Ma + Ag[node * K1 + a] + Bb;
    float kv = KB_SCALE * base;
    float tv = va ? (inv_cnt1 * 0.1f) : 0.f;
    if (a == 16) kb16 = kv;
    else if (a & 1) Kb2v[a >> 1].y = kv;
    else Kb2v[a >> 1].x = kv;
    if (a < 10) Tp2[a].x = tv; else Tp2[a - 10].y = tv;
    bw[a] = bitsG[node * K1 + a];
  }

  float2 Kc2v[8]; float k16 = 0.f;
  float2 Kr0v[5], Kr1v[5];
  float2 gr[5];
  float g2 = 0.f, fr0 = 0.f, fr1 = 0.f;

#pragma unroll 1
  for (int k = 0; k < 6; ++k) {
    // ---- stage Tp columns into KT (row-major, [a][b]) ----
#pragma unroll
    for (int a = 0; a < K1; ++a)
      KTp[a * 12 + b] = (a < 10) ? Tp2[a].x : Tp2[a - 10].y;
    CBAR();
    // ---- R = Tp @ C2^T (split chains) ----
    float R[K1];
#pragma unroll
    for (int c = 0; c < K1; ++c) {
      const float* row = &KTp[c * 12];
      float4 u0 = *(const float4*)row;
      float4 u1 = *(const float4*)(row + 4);
      float2 u2 = *(const float2*)(row + 8);
      float2 accA = pk_mul(make_float2(u0.x, u0.y), c2v[0]);
      accA = pk_fma(make_float2(u0.z, u0.w), c2v[1], accA);
      float2 accB = pk_mul(make_float2(u1.x, u1.y), c2v[2]);
      accB = pk_fma(make_float2(u1.z, u1.w), c2v[3], accB);
      accA = pk_fma(u2, c2v[4], accA);
      accA = pk_add(accA, accB);
      R[c] = accA.x + accA.y;
    }
    // ---- cross = C1 @ R via wave-uniform bitmasks → logK column ----
#pragma unroll
    for (int a = 0; a < K1; ++a) {
      float cr = 0.f;
      unsigned int m = bw[a];
      if (m) {
#pragma unroll
        for (int c = 0; c < K1; ++c)
          if (m & (1u << c)) cr += R[c];
      }
      float base = (a == 16) ? kb16 : ((a & 1) ? Kb2v[a >> 1].y : Kb2v[a >> 1].x);
      float val = base + CR_SCALE * cr;
      if (a == 16) k16 = val;
      else if (a & 1) Kc2v[a >> 1].y = val;
      else Kc2v[a >> 1].x = val;
    }

    if (k == 5) {  // final distance
      float acc = 0.f;
#pragma unroll
      for (int a = 0; a < K1; ++a) {
        bool va = (a == 0) || (a - 1 < kc);
        int sa = Sg[node * K1 + a];
        float Ma = (va ? (nxv[sa] - 2.f * dots[(size_t)sa * (NT * TN) + tb]) : 0.f) + nf2b;
        float kcv = (a == 16) ? k16 : ((a & 1) ? Kc2v[a >> 1].y : Kc2v[a >> 1].x);
        float tpv = (a < 10) ? Tp2[a].x : Tp2[a - 10].y;
        acc += tpv * (0.25f * Ma + 0.5f * (G_SCALE * kcv));
      }
      accL[wv][p][b] = acc;
      CBAR();
      if (lane < 5) {
        float s = 0.f;
#pragma unroll
        for (int j = 0; j < TN; ++j) s += accL[wv][lane][j];
        out[node * NT + wv * 5 + lane] = s;
      }
      return;
    }

    // ---- stage logK, read back rows b and 10+b ----
    CBAR();
#pragma unroll
    for (int a = 0; a < 16; ++a) KTp[a * 12 + b] = (a & 1) ? Kc2v[a >> 1].y : Kc2v[a >> 1].x;
    KTp[16 * 12 + b] = k16;
    CBAR();
    {
      const float* r0 = &KTp[b * 12];
      float4 u0 = *(const float4*)r0;
      float4 u1 = *(const float4*)(r0 + 4);
      float2 u2 = *(const float2*)(r0 + 8);
      Kr0v[0] = make_float2(u0.x, u0.y); Kr0v[1] = make_float2(u0.z, u0.w);
      Kr0v[2] = make_float2(u1.x, u1.y); Kr0v[3] = make_float2(u1.z, u1.w);
      Kr0v[4] = u2;
      const float* r1 = &KTp[(10 + b) * 12];  // b>=7: in-bounds junk (finite), row is dummy
      float4 w0 = *(const float4*)r1;
      float4 w1 = *(const float4*)(r1 + 4);
      float2 w2 = *(const float2*)(r1 + 8);
      Kr1v[0] = make_float2(w0.x, w0.y); Kr1v[1] = make_float2(w0.z, w0.w);
      Kr1v[2] = make_float2(w1.x, w1.y); Kr1v[3] = make_float2(w1.z, w1.w);
      Kr1v[4] = w2;
    }

    // ---- Sinkhorn iters 1-2 in log domain ----
#pragma unroll 1
    for (int it = 0; it < 2; ++it) {
      float2 v[8]; float v16;
      if (it == 0) {
#pragma unroll
        for (int i = 0; i < 8; ++i) v[i] = Kc2v[i];
        v16 = k16;
      } else {
        float4 f0 = *(const float4*)&fL[wv][p][0];
        float4 f1 = *(const float4*)&fL[wv][p][4];
        float4 f2 = *(const float4*)&fL[wv][p][8];
        float4 f3 = *(const float4*)&fL[wv][p][12];
        float fx = fL[wv][p][16];
        v[0] = pk_add(Kc2v[0], make_float2(f0.x, f0.y));
        v[1] = pk_add(Kc2v[1], make_float2(f0.z, f0.w));
        v[2] = pk_add(Kc2v[2], make_float2(f1.x, f1.y));
        v[3] = pk_add(Kc2v[3], make_float2(f1.z, f1.w));
        v[4] = pk_add(Kc2v[4], make_float2(f2.x, f2.y));
        v[5] = pk_add(Kc2v[5], make_float2(f2.z, f2.w));
        v[6] = pk_add(Kc2v[6], make_float2(f3.x, f3.y));
        v[7] = pk_add(Kc2v[7], make_float2(f3.z, f3.w));
        v16 = k16 + fx;
      }
      float2 m01 = pk_max(pk_max(v[0], v[1]), pk_max(v[2], v[3]));
      float2 m23 = pk_max(pk_max(v[4], v[5]), pk_max(v[6], v[7]));
      float2 mm = pk_max(m01, m23);
      float mx = fmaxf(fmaxf(mm.x, mm.y), v16);
      float2 mxb = make_float2(mx, mx);
      float2 ssA = pk_exp2(pk_sub(v[0], mxb));
      ssA = pk_add(ssA, pk_exp2(pk_sub(v[1], mxb)));
      ssA = pk_add(ssA, pk_exp2(pk_sub(v[2], mxb)));
      ssA = pk_add(ssA, pk_exp2(pk_sub(v[3], mxb)));
      float2 ssB = pk_exp2(pk_sub(v[4], mxb));
      ssB = pk_add(ssB, pk_exp2(pk_sub(v[5], mxb)));
      ssB = pk_add(ssB, pk_exp2(pk_sub(v[6], mxb)));
      ssB = pk_add(ssB, pk_exp2(pk_sub(v[7], mxb)));
      float2 ss = pk_add(ssA, ssB);
      float s = ss.x + ss.y + EXP2F(v16 - mx);
      g2 = LOGQ2 - mx - LOG2F(s);
      gL[wv][p][b] = g2;
      CBAR();
      {
        float4 g0 = *(const float4*)&gL[wv][p][0];
        float4 g1 = *(const float4*)&gL[wv][p][4];
        float2 gx = *(const float2*)&gL[wv][p][8];
        gr[0] = make_float2(g0.x, g0.y); gr[1] = make_float2(g0.z, g0.w);
        gr[2] = make_float2(g1.x, g1.y); gr[3] = make_float2(g1.z, g1.w);
        gr[4] = gx;
      }
      float2 w0[5], w1[5];
#pragma unroll
      for (int j = 0; j < 5; ++j) w0[j] = pk_add(Kr0v[j], gr[j]);
#pragma unroll
      for (int j = 0; j < 5; ++j) w1[j] = pk_add(Kr1v[j], gr[j]);
      float2 a01 = pk_max(pk_max(w0[0], w0[1]), pk_max(w0[2], w0[3]));
      a01 = pk_max(a01, w0[4]);
      float mxa = fmaxf(a01.x, a01.y);
      float2 b01 = pk_max(pk_max(w1[0], w1[1]), pk_max(w1[2], w1[3]));
      b01 = pk_max(b01, w1[4]);
      float mxb2 = fmaxf(b01.x, b01.y);
      float2 mab = make_float2(mxa, mxa);
      float2 mbb = make_float2(mxb2, mxb2);
      float2 sx = pk_exp2(pk_sub(w0[0], mab));
      sx = pk_add(sx, pk_exp2(pk_sub(w0[1], mab)));
      sx = pk_add(sx, pk_exp2(pk_sub(w0[2], mab)));
      sx = pk_add(sx, pk_exp2(pk_sub(w0[3], mab)));
      sx = pk_add(sx, pk_exp2(pk_sub(w0[4], mab)));
      float2 sy = pk_exp2(pk_sub(w1[0], mbb));
      sy = pk_add(sy, pk_exp2(pk_sub(w1[1], mbb)));
      sy = pk_add(sy, pk_exp2(pk_sub(w1[2], mbb)));
      sy = pk_add(sy, pk_exp2(pk_sub(w1[3], mbb)));
      sy = pk_add(sy, pk_exp2(pk_sub(w1[4], mbb)));
      fr0 = lp2_r0 - mxa - LOG2F(sx.x + sx.y);
      fr1 = lp2_r1 - mxb2 - LOG2F(sy.x + sy.y);
      fL[wv][p][b] = fr0;
      fL[wv][p][10 + b] = fr1;   // b>=7 -> slots 17..19, never consumed
      CBAR();
    }

    // ---- stabilized kernels from (f2, g2) snapshot; rows re-paired (j, 10+j) ----
    float2 Kcs2[10];        // .y = 0 for j>=7 (dummy rows 17..19)
    float P00, P01, Q0;
    float2 Krs01[10];
    {
      float4 F0 = *(const float4*)&fL[wv][p][0];
      float4 F1 = *(const float4*)&fL[wv][p][4];
      float4 F2 = *(const float4*)&fL[wv][p][8];
      float4 F3 = *(const float4*)&fL[wv][p][12];
      float f16v = fL[wv][p][16];
      float fs[K1];
      fs[0] = F0.x; fs[1] = F0.y; fs[2] = F0.z; fs[3] = F0.w;
      fs[4] = F1.x; fs[5] = F1.y; fs[6] = F1.z; fs[7] = F1.w;
      fs[8] = F2.x; fs[9] = F2.y; fs[10] = F2.z; fs[11] = F2.w;
      fs[12] = F3.x; fs[13] = F3.y; fs[14] = F3.z; fs[15] = F3.w;
      fs[16] = f16v;
      float qs[K1];
#pragma unroll
      for (int a = 0; a < K1; ++a) {
        float kcv = (a == 16) ? k16 : ((a & 1) ? Kc2v[a >> 1].y : Kc2v[a >> 1].x);
        qs[a] = kcv + fs[a];
      }
      float sigma = qs[0];
#pragma unroll
      for (int a = 1; a < K1; ++a) sigma = fmaxf(sigma, qs[a]);
#pragma unroll
      for (int j = 0; j < 10; ++j) {
        float kx = EXP2F(qs[j] - sigma);
        float ky = (j < 7) ? EXP2F(qs[10 + j] - sigma) : 0.f;
        Kcs2[j] = make_float2(kx, ky);
      }
      Q0 = EXP2F(clamp120(LOGQ2 - sigma - g2));
      float2 a0[5], a1[5];
#pragma unroll
      for (int j = 0; j < 5; ++j) a0[j] = pk_add(Kr0v[j], gr[j]);
#pragma unroll
      for (int j = 0; j < 5; ++j) a1[j] = pk_add(Kr1v[j], gr[j]);
      float2 r0m = pk_max(pk_max(a0[0], a0[1]), pk_max(a0[2], a0[3]));
      r0m = pk_max(r0m, a0[4]);
      float rho0 = fmaxf(r0m.x, r0m.y);
      float2 r1m = pk_max(pk_max(a1[0], a1[1]), pk_max(a1[2], a1[3]));
      r1m = pk_max(r1m, a1[4]);
      float rho1 = fmaxf(r1m.x, r1m.y);
#pragma unroll
      for (int j = 0; j < 5; ++j) {
        Krs01[2 * j]     = make_float2(EXP2F(a0[j].x - rho0), EXP2F(a1[j].x - rho1));
        Krs01[2 * j + 1] = make_float2(EXP2F(a0[j].y - rho0), EXP2F(a1[j].y - rho1));
      }
      P00 = EXP2F(clamp120((lp2_r0 - rho0) - fr0));
      P01 = EXP2F(clamp120((lp2_r1 - rho1) - fr1));
    }

    // ---- Sinkhorn iters 3..20: pure multiplicative, duplicated-w exchange ----
    float Slast, t0, t1;
    {  // peeled iter 3: u == 1
      float2 SA = pk_add(pk_add(Kcs2[0], Kcs2[1]), pk_add(Kcs2[2], Kcs2[3]));
      float2 SB = pk_add(pk_add(Kcs2[4], Kcs2[5]), pk_add(Kcs2[6], Kcs2[7]));
      float2 S2 = pk_add(pk_add(SA, SB), pk_add(Kcs2[8], Kcs2[9]));
      float S = fmaxf(S2.x + S2.y, TINYF);
      Slast = S;
      float wb = Q0 * RCPF(S);
      *(float2*)&wL[wv][p][2 * b] = make_float2(wb, wb);
      CBAR();
      float4 W0 = *(const float4*)&wL[wv][p][0];
      float4 W1 = *(const float4*)&wL[wv][p][4];
      float4 W2 = *(const float4*)&wL[wv][p][8];
      float4 W3 = *(const float4*)&wL[wv][p][12];
      float4 W4 = *(const float4*)&wL[wv][p][16];
      float2 tA = pk_mul(Krs01[0], make_float2(W0.x, W0.y));
      tA = pk_fma(Krs01[1], make_float2(W0.z, W0.w), tA);
      tA = pk_fma(Krs01[2], make_float2(W1.x, W1.y), tA);
      tA = pk_fma(Krs01[3], make_float2(W1.z, W1.w), tA);
      tA = pk_fma(Krs01[4], make_float2(W2.x, W2.y), tA);
      float2 tB = pk_mul(Krs01[5], make_float2(W2.z, W2.w));
      tB = pk_fma(Krs01[6], make_float2(W3.x, W3.y), tB);
      tB = pk_fma(Krs01[7], make_float2(W3.z, W3.w), tB);
      tB = pk_fma(Krs01[8], make_float2(W4.x, W4.y), tB);
      tB = pk_fma(Krs01[9], make_float2(W4.z, W4.w), tB);
      float2 t01 = pk_add(tA, tB);
      t0 = t01.x; t1 = t01.y;
    }
#pragma unroll 1
    for (int it = 0; it < 17; ++it) {   // iters 4..20
      float u0 = P00 * RCPF(fmaxf(t0, TINYF));
      float u1 = P01 * RCPF(fmaxf(t1, TINYF));
      *(float2*)&uL[wv][p][2 * b] = make_float2(u0, u1);   // ONE b64 write
      CBAR();
      float4 U0 = *(const float4*)&uL[wv][p][0];    // (u0,u10, u1,u11)
      float4 U1 = *(const float4*)&uL[wv][p][4];
      float4 U2 = *(const float4*)&uL[wv][p][8];
      float4 U3 = *(const float4*)&uL[wv][p][12];
      float4 U4 = *(const float4*)&uL[wv][p][16];
      float2 SA = pk_mul(Kcs2[0], make_float2(U0.x, U0.y));
      SA = pk_fma(Kcs2[1], make_float2(U0.z, U0.w), SA);
      SA = pk_fma(Kcs2[2], make_float2(U1.x, U1.y), SA);
      SA = pk_fma(Kcs2[3], make_float2(U1.z, U1.w), SA);
      SA = pk_fma(Kcs2[4], make_float2(U2.x, U2.y), SA);
      float2 SB = pk_mul(Kcs2[5], make_float2(U2.z, U2.w));
      SB = pk_fma(Kcs2[6], make_float2(U3.x, U3.y), SB);
      SB = pk_fma(Kcs2[7], make_float2(U3.z, U3.w), SB);
      SB = pk_fma(Kcs2[8], make_float2(U4.x, U4.y), SB);
      SB = pk_fma(Kcs2[9], make_float2(U4.z, U4.w), SB);
      float2 S2 = pk_add(SA, SB);
      float S = fmaxf(S2.x + S2.y, TINYF);
      Slast = S;
      float wb = Q0 * RCPF(S);
      *(float2*)&wL[wv][p][2 * b] = make_float2(wb, wb);
      CBAR();
      float4 W0 = *(const float4*)&wL[wv][p][0];
      float4 W1 = *(const float4*)&wL[wv][p][4];
      float4 W2 = *(const float4*)&wL[wv][p][8];
      float4 W3 = *(const float4*)&wL[wv][p][12];
      float4 W4 = *(const float4*)&wL[wv][p][16];
      float2 tA = pk_mul(Krs01[0], make_float2(W0.x, W0.y));
      tA = pk_fma(Krs01[1], make_float2(W0.z, W0.w), tA);
      tA = pk_fma(Krs01[2], make_float2(W1.x, W1.y), tA);
      tA = pk_fma(Krs01[3], make_float2(W1.z, W1.w), tA);
      tA = pk_fma(Krs01[4], make_float2(W2.x, W2.y), tA);
      float2 tB = pk_mul(Krs01[5], make_float2(W2.z, W2.w));
      tB = pk_fma(Krs01[6], make_float2(W3.x, W3.y), tB);
      tB = pk_fma(Krs01[7], make_float2(W3.z, W3.w), tB);
      tB = pk_fma(Krs01[8], make_float2(W4.x, W4.y), tB);
      tB = pk_fma(Krs01[9], make_float2(W4.z, W4.w), tB);
      float2 t01 = pk_add(tA, tB);
      t0 = t01.x; t1 = t01.y;
    }

    // ---- final u + FW transport update: Tn = u * Kcs * (0.1/Slast), pairing matches ----
    {
      float u0 = P00 * RCPF(fmaxf(t0, TINYF));
      float u1 = P01 * RCPF(fmaxf(t1, TINYF));
      *(float2*)&uL[wv][p][2 * b] = make_float2(u0, u1);
      CBAR();
      float4 U0 = *(const float4*)&uL[wv][p][0];
      float4 U1 = *(const float4*)&uL[wv][p][4];
      float4 U2 = *(const float4*)&uL[wv][p][8];
      float4 U3 = *(const float4*)&uL[wv][p][12];
      float4 U4 = *(const float4*)&uL[wv][p][16];
      const float gam = 2.f / ((float)k + 2.f);
      const float gs = gam * 0.1f * RCPF(Slast);
      const float om = 1.f - gam;
      const float2 omb = make_float2(om, om);
      const float2 gsb = make_float2(gs, gs);
      float2 uu[10];
      uu[0] = make_float2(U0.x, U0.y); uu[1] = make_float2(U0.z, U0.w);
      uu[2] = make_float2(U1.x, U1.y); uu[3] = make_float2(U1.z, U1.w);
      uu[4] = make_float2(U2.x, U2.y); uu[5] = make_float2(U2.z, U2.w);
      uu[6] = make_float2(U3.x, U3.y); uu[7] = make_float2(U3.z, U3.w);
      uu[8] = make_float2(U4.x, U4.y); uu[9] = make_float2(U4.z, U4.w);
#pragma unroll
      for (int j = 0; j < 10; ++j)
        Tp2[j] = pk_fma(omb, Tp2[j], pk_mul(gsb, pk_mul(Kcs2[j], uu[j])));
    }
  }
}

extern "C" void kernel_launch(void* const* d_in, const int* in_sizes, int n_in,
                              void* d_out, int out_size, void* d_ws, size_t ws_size,
                              hipStream_t stream) {
  const float* x    = (const float*)d_in[0];
  const int*   ei   = (const int*)d_in[1];
  const float* tmpl = (const float*)d_in[2];
  const float* tf   = (const float*)d_in[3];
  float* out = (float*)d_out;

  int* cnt  = (int*)d_ws;
  int* ebuf = cnt + NNODE;
  int* nbrs = ebuf + (size_t)NNODE * CAP;
  int* kcnt = nbrs + (size_t)NNODE * KNB;
  int* Sg   = kcnt + NNODE;
  unsigned int* bits = (unsigned int*)(Sg + (size_t)NNODE * K1);
  float* Ag   = (float*)(bits + (size_t)NNODE * K1);
  float* dots = Ag + (size_t)NNODE * K1;
  float* nxv  = dots + (size_t)NNODE * (NT * TN);
  float* nF2  = nxv + NNODE;
  float* Bq   = nF2 + NT * TN;

  hipMemsetAsync(cnt, 0, NNODE * sizeof(int), stream);
  k_prep<<<625 + (NNODE + 15) / 16, 256, 0, stream>>>(ei, cnt, ebuf, x, tf, tmpl,
                                                      dots, nxv, nF2, Bq);
  k_select<<<(NNODE + 3) / 4, 256, 0, stream>>>(ei, cnt, ebuf, nbrs, kcnt, Sg);
  k_c1b<<<(NNODE * K1 + 255) / 256, 256, 0, stream>>>(nbrs, kcnt, Sg, bits, Ag);
  k_main<<<NNODE, 128, 0, stream>>>(tmpl, kcnt, Sg, bits, Ag, dots, nxv, nF2, Bq, out);
}

// Round 14
// 541.783 us; speedup vs baseline: 1.1652x; 1.0123x over previous
//
#include <hip/hip_runtime.h>
#include <math.h>

#define NNODE 10000
#define NEDGE 160000
#define KNB   16
#define K1    17
#define NT    10
#define TN    10
#define DF    128
#define CAP   64
#define NEG_BIG (-1e9f)

#define LOGQ2      (-3.32192809489f)   /* log2(0.1) */
#define KB_SCALE   (-14.4269504089f)   /* -10*log2e  */
#define CR_SCALE   (28.8539008178f)    /* +20*log2e  */
#define G_SCALE    (-0.069314718056f)  /* -ln2/10    */
#define LN2        0.69314718056f
#define TINYF      1e-30f

#if defined(__has_builtin)
#if __has_builtin(__builtin_amdgcn_exp2f)
#define EXP2F(x) __builtin_amdgcn_exp2f(x)
#endif
#if __has_builtin(__builtin_amdgcn_rcpf)
#define RCPF(x) __builtin_amdgcn_rcpf(x)
#endif
#endif
#ifndef EXP2F
#define EXP2F(x) __expf((x) * LN2)
#endif
#ifndef RCPF
#define RCPF(x) (1.0f / (x))
#endif
#define LOG2F(x) __log2f(x)

// Compiler-only barrier: DS ops from one wave execute IN ORDER in the LDS
// pipeline; compiler still emits lgkmcnt(N) before VALU consumes read data.
#define CBAR() asm volatile("" ::: "memory")

__device__ __forceinline__ float2 pk_add(float2 a, float2 b) { return make_float2(a.x + b.x, a.y + b.y); }
__device__ __forceinline__ float2 pk_sub(float2 a, float2 b) { return make_float2(a.x - b.x, a.y - b.y); }
__device__ __forceinline__ float2 pk_mul(float2 a, float2 b) { return make_float2(a.x * b.x, a.y * b.y); }
__device__ __forceinline__ float2 pk_max(float2 a, float2 b) { return make_float2(fmaxf(a.x, b.x), fmaxf(a.y, b.y)); }
__device__ __forceinline__ float2 pk_fma(float2 a, float2 b, float2 c) { return make_float2(fmaf(a.x, b.x, c.x), fmaf(a.y, b.y, c.y)); }
__device__ __forceinline__ float2 pk_exp2(float2 a) { return make_float2(EXP2F(a.x), EXP2F(a.y)); }
__device__ __forceinline__ float clamp120(float x) { return fminf(120.f, fmaxf(-120.f, x)); }

// int64-vs-int32 sniff, computed by ONE lane and broadcast
__device__ __forceinline__ int detect_wide_wave(const int* ei) {
  int z = 0;
  if ((threadIdx.x & 63) == 0) {
#pragma unroll
    for (int i = 0; i < 32; ++i) z |= ei[2 * i + 1];
  }
  z = __shfl(z, 0, 64);
  return z == 0;
}

// ---------- fused: edge bucketing + feature dots (16-node tiles) + template stats ----------
__global__ void __launch_bounds__(256) k_prep(const int* __restrict__ ei,
                                              int* cnt, int* ebuf,
                                              const float* __restrict__ x,
                                              const float* __restrict__ tf,
                                              const float* __restrict__ tmpl,
                                              float* __restrict__ dots,
                                              float* __restrict__ nxv,
                                              float* __restrict__ nF2,
                                              float* __restrict__ Bq) {
  __shared__ float xs[16][DF];   // 8 KB
  const int tid = threadIdx.x;
  if (blockIdx.x < 625) {          // hist: 625*256 == NEDGE
    int wide = detect_wide_wave(ei);
    int e = blockIdx.x * 256 + tid;
    int s = wide ? ei[2 * e] : ei[e];
    int pos = atomicAdd(&cnt[s], 1);
    if (pos < CAP) ebuf[s * CAP + pos] = e;   // node-major: wave-coalesced select reads
    return;
  }
  const int db = blockIdx.x - 625;
  if (db == 0 && tid < NT * TN) {  // template stats, once
    const float* fp = tf + (size_t)tid * DF;
    float s = 0.f;
    for (int d = 0; d < DF; ++d) { float v = fp[d]; s += v * v; }
    nF2[tid] = s;
    const float* cp = tmpl + (size_t)tid * TN;
    float s2 = 0.f;
    for (int c = 0; c < TN; ++c) { float v = cp[c]; s2 += v * v; }
    Bq[tid] = 0.1f * s2;
  }
  const int nb = db * 16;
  const int nvalid = (NNODE - nb) < 16 ? (NNODE - nb) : 16;
  {
    const float4* xg = (const float4*)(x + (size_t)nb * DF);
    float4* xl = (float4*)&xs[0][0];
    for (int i = tid; i < nvalid * (DF / 4); i += 256) xl[i] = xg[i];
  }
  __syncthreads();
  for (int o = tid; o < nvalid * (NT * TN); o += 256) {
    int n = o / (NT * TN);
    int tb = o - n * (NT * TN);
    const float4* fp = (const float4*)(tf + (size_t)tb * DF);
    const float4* xp = (const float4*)&xs[n][0];
    float s = 0.f;
#pragma unroll
    for (int d = 0; d < DF / 4; ++d) {
      float4 a = xp[d], f = fp[d];
      s += a.x * f.x + a.y * f.y + a.z * f.z + a.w * f.w;
    }
    dots[(size_t)(nb + n) * (NT * TN) + tb] = s;
  }
  if (tid < nvalid) {
    const float4* xp = (const float4*)&xs[tid][0];
    float s = 0.f;
#pragma unroll
    for (int d = 0; d < DF / 4; ++d) {
      float4 a = xp[d];
      s += a.x * a.x + a.y * a.y + a.z * a.z + a.w * a.w;
    }
    nxv[nb + tid] = s;
  }
}

// ---------- wave-per-node: bitonic-sort 64 bucket entries, keep 16 smallest ----------
__global__ void __launch_bounds__(256) k_select(const int* __restrict__ ei,
                                                const int* __restrict__ cnt,
                                                const int* __restrict__ ebuf,
                                                int* __restrict__ nbrs,
                                                int* __restrict__ kcnt,
                                                int* __restrict__ Sg) {
  const int wv = threadIdx.x >> 6;
  const int lane = threadIdx.x & 63;
  const int i = blockIdx.x * 4 + wv;
  if (i >= NNODE) return;
  const int wide = detect_wide_wave(ei);
  int c = cnt[i]; c = c > CAP ? CAP : c;
  int v = (lane < c) ? ebuf[i * CAP + lane] : 0x7FFFFFFF;
#pragma unroll
  for (int k = 2; k <= 64; k <<= 1) {
#pragma unroll
    for (int j = k >> 1; j > 0; j >>= 1) {
      int pv = __shfl_xor(v, j, 64);
      bool up = ((lane & k) == 0);
      bool lower = ((lane & j) == 0);
      int mn = v < pv ? v : pv;
      int mx = v < pv ? pv : v;
      v = (lower == up) ? mn : mx;
    }
  }
  const int m = c < KNB ? c : KNB;
  if (lane == 0) { kcnt[i] = m; Sg[i * K1] = i; }
  if (lane < KNB) {
    int d = 0;
    if (lane < m) d = wide ? ei[2 * (NEDGE + v)] : ei[NEDGE + v];
    nbrs[i * KNB + lane] = d;
    Sg[i * K1 + 1 + lane] = d;
  }
}

// ---------- C1 bitmasks: one thread per (node, row) ----------
__global__ void __launch_bounds__(256) k_c1b(const int* __restrict__ nbrs,
                                             const int* __restrict__ kcnt,
                                             const int* __restrict__ Sg,
                                             unsigned int* __restrict__ bitsG,
                                             float* __restrict__ Ag) {
  int idx = blockIdx.x * 256 + threadIdx.x;
  if (idx >= NNODE * K1) return;
  int i = idx / K1;
  int a = idx - i * K1;
  int kc = kcnt[i];
  unsigned int vmask = (kc >= KNB) ? 0x1FFFFu : ((2u << kc) - 1u);
  unsigned int bits = 0;
  bool va = (a == 0) || (a - 1 < kc);
  if (va) {
    int S[K1];
#pragma unroll
    for (int b = 0; b < K1; ++b) S[b] = Sg[i * K1 + b];
    int u = S[a];
    int ku = kcnt[u];
    const int* np = nbrs + (size_t)u * KNB;
    for (int j = 0; j < ku; ++j) {
      int w = np[j];
#pragma unroll
      for (int b = 0; b < K1; ++b) bits |= (S[b] == w) ? (1u << b) : 0u;
    }
    bits &= vmask;
  }
  bitsG[idx] = bits;
  Ag[idx] = (float)__popc(bits) / (float)(1 + kc);
}

// ---------- FGW main: block = node, 2 waves x 5 pairs (+dummy slot 5), branch-free LDS ----------
__global__ void __launch_bounds__(128, 3) k_main(
    const float* __restrict__ tmpl,
    const int* __restrict__ kcnt, const int* __restrict__ Sg,
    const unsigned int* __restrict__ bitsG, const float* __restrict__ Ag,
    const float* __restrict__ dots, const float* __restrict__ nxv,
    const float* __restrict__ nF2, const float* __restrict__ Bq,
    float* __restrict__ out)
{
  __shared__ float KT[2 * 6 * 204 + 48];  // 6 slots/wave (slot 5 = dummy); stride 204 ≡ 12 mod 32
  __shared__ float fL[2][6][20];
  __shared__ float gL[2][6][12];
  __shared__ float uL[2][6][20];          // b64 pairs (u_j, u_{10+j})
  __shared__ float wL[2][6][12];          // COMPACT w (10 floats): LDS pipe is the scarce resource
  __shared__ float accL[2][6][TN];

  const int wv = threadIdx.x >> 6;       // 0..1 = template half
  const int lane = threadIdx.x & 63;
  const int p0 = lane / 10;
  const int b = lane - p0 * 10;
  const bool act = (p0 < 5);
  const int p = act ? p0 : 5;            // inactive lanes -> dummy LDS slot
  const int node = blockIdx.x;           // wave-uniform
  const int tb = act ? ((wv * 5 + p0) * TN + b) : 0;   // clamp: no OOB global reads
  float* KTp = &KT[(wv * 6 + p) * 204];

  const int kc = kcnt[node];
  const float cnt1 = (float)(1 + kc);
  const float inv_cnt1 = 1.f / cnt1;
  const float logp2v = -LOG2F(cnt1);
  const float lp2_r0 = ((b == 0) || (b - 1 < kc)) ? logp2v : NEG_BIG;  // row b
  const float lp2_r1 = ((9 + b) < kc) ? logp2v : NEG_BIG;              // row 10+b (b>=7: dummy)

  float2 c2v[5];
  {
    const float2* cp = (const float2*)(tmpl + (size_t)tb * TN);
#pragma unroll
    for (int j = 0; j < 5; ++j) c2v[j] = cp[j];
  }
  const float Bb = Bq[tb];
  const float nf2b = nF2[tb];

  float2 Kb2v[8]; float kb16;           // (2i,2i+1) pairing for log phase
  float2 Tp2[10];                       // (j, 10+j) pairing; .y=0 for j>=7 (dummy rows)
#pragma unroll
  for (int j = 0; j < 10; ++j) Tp2[j] = make_float2(0.f, 0.f);
  unsigned int bw[K1];
#pragma unroll
  for (int a = 0; a < K1; ++a) {
    bool va = (a == 0) || (a - 1 < kc);
    int sa = Sg[node * K1 + a];
    float Ma = (va ? (nxv[sa] - 2.f * dots[(size_t)sa * (NT * TN) + tb]) : 0.f) + nf2b;
    float base = 0.5f * Ma + Ag[node * K1 + a] + Bb;
    float kv = KB_SCALE * base;
    float tv = va ? (inv_cnt1 * 0.1f) : 0.f;
    if (a == 16) kb16 = kv;
    else if (a & 1) Kb2v[a >> 1].y = kv;
    else Kb2v[a >> 1].x = kv;
    if (a < 10) Tp2[a].x = tv; else Tp2[a - 10].y = tv;
    bw[a] = bitsG[node * K1 + a];
  }

  float2 Kc2v[8]; float k16 = 0.f;
  float2 Kr0v[5], Kr1v[5];
  float2 gr[5];
  float g2 = 0.f, fr0 = 0.f, fr1 = 0.f;

#pragma unroll 1
  for (int k = 0; k < 6; ++k) {
    // ---- stage Tp columns into KT (row-major, [a][b]) ----
#pragma unroll
    for (int a = 0; a < K1; ++a)
      KTp[a * 12 + b] = (a < 10) ? Tp2[a].x : Tp2[a - 10].y;
    CBAR();
    // ---- R = Tp @ C2^T (split chains) ----
    float R[K1];
#pragma unroll
    for (int c = 0; c < K1; ++c) {
      const float* row = &KTp[c * 12];
      float4 u0 = *(const float4*)row;
      float4 u1 = *(const float4*)(row + 4);
      float2 u2 = *(const float2*)(row + 8);
      float2 accA = pk_mul(make_float2(u0.x, u0.y), c2v[0]);
      accA = pk_fma(make_float2(u0.z, u0.w), c2v[1], accA);
      float2 accB = pk_mul(make_float2(u1.x, u1.y), c2v[2]);
      accB = pk_fma(make_float2(u1.z, u1.w), c2v[3], accB);
      accA = pk_fma(u2, c2v[4], accA);
      accA = pk_add(accA, accB);
      R[c] = accA.x + accA.y;
    }
    // ---- cross = C1 @ R via wave-uniform bitmasks → logK column ----
#pragma unroll
    for (int a = 0; a < K1; ++a) {
      float cr = 0.f;
      unsigned int m = bw[a];
      if (m) {
#pragma unroll
        for (int c = 0; c < K1; ++c)
          if (m & (1u << c)) cr += R[c];
      }
      float base = (a == 16) ? kb16 : ((a & 1) ? Kb2v[a >> 1].y : Kb2v[a >> 1].x);
      float val = base + CR_SCALE * cr;
      if (a == 16) k16 = val;
      else if (a & 1) Kc2v[a >> 1].y = val;
      else Kc2v[a >> 1].x = val;
    }

    if (k == 5) {  // final distance
      float acc = 0.f;
#pragma unroll
      for (int a = 0; a < K1; ++a) {
        bool va = (a == 0) || (a - 1 < kc);
        int sa = Sg[node * K1 + a];
        float Ma = (va ? (nxv[sa] - 2.f * dots[(size_t)sa * (NT * TN) + tb]) : 0.f) + nf2b;
        float kcv = (a == 16) ? k16 : ((a & 1) ? Kc2v[a >> 1].y : Kc2v[a >> 1].x);
        float tpv = (a < 10) ? Tp2[a].x : Tp2[a - 10].y;
        acc += tpv * (0.25f * Ma + 0.5f * (G_SCALE * kcv));
      }
      accL[wv][p][b] = acc;
      CBAR();
      if (lane < 5) {
        float s = 0.f;
#pragma unroll
        for (int j = 0; j < TN; ++j) s += accL[wv][lane][j];
        out[node * NT + wv * 5 + lane] = s;
      }
      return;
    }

    // ---- stage logK, read back rows b and 10+b ----
    CBAR();
#pragma unroll
    for (int a = 0; a < 16; ++a) KTp[a * 12 + b] = (a & 1) ? Kc2v[a >> 1].y : Kc2v[a >> 1].x;
    KTp[16 * 12 + b] = k16;
    CBAR();
    {
      const float* r0 = &KTp[b * 12];
      float4 u0 = *(const float4*)r0;
      float4 u1 = *(const float4*)(r0 + 4);
      float2 u2 = *(const float2*)(r0 + 8);
      Kr0v[0] = make_float2(u0.x, u0.y); Kr0v[1] = make_float2(u0.z, u0.w);
      Kr0v[2] = make_float2(u1.x, u1.y); Kr0v[3] = make_float2(u1.z, u1.w);
      Kr0v[4] = u2;
      const float* r1 = &KTp[(10 + b) * 12];  // b>=7: in-bounds junk (finite), row is dummy
      float4 w0 = *(const float4*)r1;
      float4 w1 = *(const float4*)(r1 + 4);
      float2 w2 = *(const float2*)(r1 + 8);
      Kr1v[0] = make_float2(w0.x, w0.y); Kr1v[1] = make_float2(w0.z, w0.w);
      Kr1v[2] = make_float2(w1.x, w1.y); Kr1v[3] = make_float2(w1.z, w1.w);
      Kr1v[4] = w2;
    }

    // ---- Sinkhorn iters 1-2 in log domain ----
#pragma unroll 1
    for (int it = 0; it < 2; ++it) {
      float2 v[8]; float v16;
      if (it == 0) {
#pragma unroll
        for (int i = 0; i < 8; ++i) v[i] = Kc2v[i];
        v16 = k16;
      } else {
        float4 f0 = *(const float4*)&fL[wv][p][0];
        float4 f1 = *(const float4*)&fL[wv][p][4];
        float4 f2 = *(const float4*)&fL[wv][p][8];
        float4 f3 = *(const float4*)&fL[wv][p][12];
        float fx = fL[wv][p][16];
        v[0] = pk_add(Kc2v[0], make_float2(f0.x, f0.y));
        v[1] = pk_add(Kc2v[1], make_float2(f0.z, f0.w));
        v[2] = pk_add(Kc2v[2], make_float2(f1.x, f1.y));
        v[3] = pk_add(Kc2v[3], make_float2(f1.z, f1.w));
        v[4] = pk_add(Kc2v[4], make_float2(f2.x, f2.y));
        v[5] = pk_add(Kc2v[5], make_float2(f2.z, f2.w));
        v[6] = pk_add(Kc2v[6], make_float2(f3.x, f3.y));
        v[7] = pk_add(Kc2v[7], make_float2(f3.z, f3.w));
        v16 = k16 + fx;
      }
      float2 m01 = pk_max(pk_max(v[0], v[1]), pk_max(v[2], v[3]));
      float2 m23 = pk_max(pk_max(v[4], v[5]), pk_max(v[6], v[7]));
      float2 mm = pk_max(m01, m23);
      float mx = fmaxf(fmaxf(mm.x, mm.y), v16);
      float2 mxb = make_float2(mx, mx);
      float2 ssA = pk_exp2(pk_sub(v[0], mxb));
      ssA = pk_add(ssA, pk_exp2(pk_sub(v[1], mxb)));
      ssA = pk_add(ssA, pk_exp2(pk_sub(v[2], mxb)));
      ssA = pk_add(ssA, pk_exp2(pk_sub(v[3], mxb)));
      float2 ssB = pk_exp2(pk_sub(v[4], mxb));
      ssB = pk_add(ssB, pk_exp2(pk_sub(v[5], mxb)));
      ssB = pk_add(ssB, pk_exp2(pk_sub(v[6], mxb)));
      ssB = pk_add(ssB, pk_exp2(pk_sub(v[7], mxb)));
      float2 ss = pk_add(ssA, ssB);
      float s = ss.x + ss.y + EXP2F(v16 - mx);
      g2 = LOGQ2 - mx - LOG2F(s);
      gL[wv][p][b] = g2;
      CBAR();
      {
        float4 g0 = *(const float4*)&gL[wv][p][0];
        float4 g1 = *(const float4*)&gL[wv][p][4];
        float2 gx = *(const float2*)&gL[wv][p][8];
        gr[0] = make_float2(g0.x, g0.y); gr[1] = make_float2(g0.z, g0.w);
        gr[2] = make_float2(g1.x, g1.y); gr[3] = make_float2(g1.z, g1.w);
        gr[4] = gx;
      }
      float2 w0[5], w1[5];
#pragma unroll
      for (int j = 0; j < 5; ++j) w0[j] = pk_add(Kr0v[j], gr[j]);
#pragma unroll
      for (int j = 0; j < 5; ++j) w1[j] = pk_add(Kr1v[j], gr[j]);
      float2 a01 = pk_max(pk_max(w0[0], w0[1]), pk_max(w0[2], w0[3]));
      a01 = pk_max(a01, w0[4]);
      float mxa = fmaxf(a01.x, a01.y);
      float2 b01 = pk_max(pk_max(w1[0], w1[1]), pk_max(w1[2], w1[3]));
      b01 = pk_max(b01, w1[4]);
      float mxb2 = fmaxf(b01.x, b01.y);
      float2 mab = make_float2(mxa, mxa);
      float2 mbb = make_float2(mxb2, mxb2);
      float2 sx = pk_exp2(pk_sub(w0[0], mab));
      sx = pk_add(sx, pk_exp2(pk_sub(w0[1], mab)));
      sx = pk_add(sx, pk_exp2(pk_sub(w0[2], mab)));
      sx = pk_add(sx, pk_exp2(pk_sub(w0[3], mab)));
      sx = pk_add(sx, pk_exp2(pk_sub(w0[4], mab)));
      float2 sy = pk_exp2(pk_sub(w1[0], mbb));
      sy = pk_add(sy, pk_exp2(pk_sub(w1[1], mbb)));
      sy = pk_add(sy, pk_exp2(pk_sub(w1[2], mbb)));
      sy = pk_add(sy, pk_exp2(pk_sub(w1[3], mbb)));
      sy = pk_add(sy, pk_exp2(pk_sub(w1[4], mbb)));
      fr0 = lp2_r0 - mxa - LOG2F(sx.x + sx.y);
      fr1 = lp2_r1 - mxb2 - LOG2F(sy.x + sy.y);
      fL[wv][p][b] = fr0;
      fL[wv][p][10 + b] = fr1;   // b>=7 -> slots 17..19, never consumed
      CBAR();
    }

    // ---- stabilized kernels from (f2, g2) snapshot; rows re-paired (j, 10+j) ----
    float2 Kcs2[10];        // .y = 0 for j>=7 (dummy rows 17..19)
    float P00, P01, Q0;
    float2 Krs01[10];
    {
      float4 F0 = *(const float4*)&fL[wv][p][0];
      float4 F1 = *(const float4*)&fL[wv][p][4];
      float4 F2 = *(const float4*)&fL[wv][p][8];
      float4 F3 = *(const float4*)&fL[wv][p][12];
      float f16v = fL[wv][p][16];
      float fs[K1];
      fs[0] = F0.x; fs[1] = F0.y; fs[2] = F0.z; fs[3] = F0.w;
      fs[4] = F1.x; fs[5] = F1.y; fs[6] = F1.z; fs[7] = F1.w;
      fs[8] = F2.x; fs[9] = F2.y; fs[10] = F2.z; fs[11] = F2.w;
      fs[12] = F3.x; fs[13] = F3.y; fs[14] = F3.z; fs[15] = F3.w;
      fs[16] = f16v;
      float qs[K1];
#pragma unroll
      for (int a = 0; a < K1; ++a) {
        float kcv = (a == 16) ? k16 : ((a & 1) ? Kc2v[a >> 1].y : Kc2v[a >> 1].x);
        qs[a] = kcv + fs[a];
      }
      float sigma = qs[0];
#pragma unroll
      for (int a = 1; a < K1; ++a) sigma = fmaxf(sigma, qs[a]);
#pragma unroll
      for (int j = 0; j < 10; ++j) {
        float kx = EXP2F(qs[j] - sigma);
        float ky = (j < 7) ? EXP2F(qs[10 + j] - sigma) : 0.f;
        Kcs2[j] = make_float2(kx, ky);
      }
      Q0 = EXP2F(clamp120(LOGQ2 - sigma - g2));
      float2 a0[5], a1[5];
#pragma unroll
      for (int j = 0; j < 5; ++j) a0[j] = pk_add(Kr0v[j], gr[j]);
#pragma unroll
      for (int j = 0; j < 5; ++j) a1[j] = pk_add(Kr1v[j], gr[j]);
      float2 r0m = pk_max(pk_max(a0[0], a0[1]), pk_max(a0[2], a0[3]));
      r0m = pk_max(r0m, a0[4]);
      float rho0 = fmaxf(r0m.x, r0m.y);
      float2 r1m = pk_max(pk_max(a1[0], a1[1]), pk_max(a1[2], a1[3]));
      r1m = pk_max(r1m, a1[4]);
      float rho1 = fmaxf(r1m.x, r1m.y);
#pragma unroll
      for (int j = 0; j < 5; ++j) {
        Krs01[2 * j]     = make_float2(EXP2F(a0[j].x - rho0), EXP2F(a1[j].x - rho1));
        Krs01[2 * j + 1] = make_float2(EXP2F(a0[j].y - rho0), EXP2F(a1[j].y - rho1));
      }
      P00 = EXP2F(clamp120((lp2_r0 - rho0) - fr0));
      P01 = EXP2F(clamp120((lp2_r1 - rho1) - fr1));
    }

    // ---- Sinkhorn iters 3..20: pure multiplicative, compact-w exchange ----
    float Slast, t0, t1;
    {  // peeled iter 3: u == 1
      float2 SA = pk_add(pk_add(Kcs2[0], Kcs2[1]), pk_add(Kcs2[2], Kcs2[3]));
      float2 SB = pk_add(pk_add(Kcs2[4], Kcs2[5]), pk_add(Kcs2[6], Kcs2[7]));
      float2 S2 = pk_add(pk_add(SA, SB), pk_add(Kcs2[8], Kcs2[9]));
      float S = fmaxf(S2.x + S2.y, TINYF);
      Slast = S;
      float wb = Q0 * RCPF(S);
      wL[wv][p][b] = wb;
      CBAR();
      float4 W0 = *(const float4*)&wL[wv][p][0];
      float4 W1 = *(const float4*)&wL[wv][p][4];
      float2 W2 = *(const float2*)&wL[wv][p][8];
      float2 tA = pk_mul(Krs01[0], make_float2(W0.x, W0.x));
      tA = pk_fma(Krs01[1], make_float2(W0.y, W0.y), tA);
      tA = pk_fma(Krs01[2], make_float2(W0.z, W0.z), tA);
      tA = pk_fma(Krs01[3], make_float2(W0.w, W0.w), tA);
      tA = pk_fma(Krs01[4], make_float2(W1.x, W1.x), tA);
      float2 tB = pk_mul(Krs01[5], make_float2(W1.y, W1.y));
      tB = pk_fma(Krs01[6], make_float2(W1.z, W1.z), tB);
      tB = pk_fma(Krs01[7], make_float2(W1.w, W1.w), tB);
      tB = pk_fma(Krs01[8], make_float2(W2.x, W2.x), tB);
      tB = pk_fma(Krs01[9], make_float2(W2.y, W2.y), tB);
      float2 t01 = pk_add(tA, tB);
      t0 = t01.x; t1 = t01.y;
    }
#pragma unroll 1
    for (int it = 0; it < 17; ++it) {   // iters 4..20
      float u0 = P00 * RCPF(fmaxf(t0, TINYF));
      float u1 = P01 * RCPF(fmaxf(t1, TINYF));
      *(float2*)&uL[wv][p][2 * b] = make_float2(u0, u1);   // ONE b64 write
      CBAR();
      float4 U0 = *(const float4*)&uL[wv][p][0];    // (u0,u10, u1,u11)
      float4 U1 = *(const float4*)&uL[wv][p][4];
      float4 U2 = *(const float4*)&uL[wv][p][8];
      float4 U3 = *(const float4*)&uL[wv][p][12];
      float4 U4 = *(const float4*)&uL[wv][p][16];
      float2 SA = pk_mul(Kcs2[0], make_float2(U0.x, U0.y));
      SA = pk_fma(Kcs2[1], make_float2(U0.z, U0.w), SA);
      SA = pk_fma(Kcs2[2], make_float2(U1.x, U1.y), SA);
      SA = pk_fma(Kcs2[3], make_float2(U1.z, U1.w), SA);
      SA = pk_fma(Kcs2[4], make_float2(U2.x, U2.y), SA);
      float2 SB = pk_mul(Kcs2[5], make_float2(U2.z, U2.w));
      SB = pk_fma(Kcs2[6], make_float2(U3.x, U3.y), SB);
      SB = pk_fma(Kcs2[7], make_float2(U3.z, U3.w), SB);
      SB = pk_fma(Kcs2[8], make_float2(U4.x, U4.y), SB);
      SB = pk_fma(Kcs2[9], make_float2(U4.z, U4.w), SB);
      float2 S2 = pk_add(SA, SB);
      float S = fmaxf(S2.x + S2.y, TINYF);
      Slast = S;
      float wb = Q0 * RCPF(S);
      wL[wv][p][b] = wb;
      CBAR();
      float4 W0 = *(const float4*)&wL[wv][p][0];
      float4 W1 = *(const float4*)&wL[wv][p][4];
      float2 W2 = *(const float2*)&wL[wv][p][8];
      float2 tA = pk_mul(Krs01[0], make_float2(W0.x, W0.x));
      tA = pk_fma(Krs01[1], make_float2(W0.y, W0.y), tA);
      tA = pk_fma(Krs01[2], make_float2(W0.z, W0.z), tA);
      tA = pk_fma(Krs01[3], make_float2(W0.w, W0.w), tA);
      tA = pk_fma(Krs01[4], make_float2(W1.x, W1.x), tA);
      float2 tB = pk_mul(Krs01[5], make_float2(W1.y, W1.y));
      tB = pk_fma(Krs01[6], make_float2(W1.z, W1.z), tB);
      tB = pk_fma(Krs01[7], make_float2(W1.w, W1.w), tB);
      tB = pk_fma(Krs01[8], make_float2(W2.x, W2.x), tB);
      tB = pk_fma(Krs01[9], make_float2(W2.y, W2.y), tB);
      float2 t01 = pk_add(tA, tB);
      t0 = t01.x; t1 = t01.y;
    }

    // ---- final u + FW transport update: Tn = u * Kcs * (0.1/Slast), pairing matches ----
    {
      float u0 = P00 * RCPF(fmaxf(t0, TINYF));
      float u1 = P01 * RCPF(fmaxf(t1, TINYF));
      *(float2*)&uL[wv][p][2 * b] = make_float2(u0, u1);
      CBAR();
      float4 U0 = *(const float4*)&uL[wv][p][0];
      float4 U1 = *(const float4*)&uL[wv][p][4];
      float4 U2 = *(const float4*)&uL[wv][p][8];
      float4 U3 = *(const float4*)&uL[wv][p][12];
      float4 U4 = *(const float4*)&uL[wv][p][16];
      const float gam = 2.f / ((float)k + 2.f);
      const float gs = gam * 0.1f * RCPF(Slast);
      const float om = 1.f - gam;
      const float2 omb = make_float2(om, om);
      const float2 gsb = make_float2(gs, gs);
      float2 uu[10];
      uu[0] = make_float2(U0.x, U0.y); uu[1] = make_float2(U0.z, U0.w);
      uu[2] = make_float2(U1.x, U1.y); uu[3] = make_float2(U1.z, U1.w);
      uu[4] = make_float2(U2.x, U2.y); uu[5] = make_float2(U2.z, U2.w);
      uu[6] = make_float2(U3.x, U3.y); uu[7] = make_float2(U3.z, U3.w);
      uu[8] = make_float2(U4.x, U4.y); uu[9] = make_float2(U4.z, U4.w);
#pragma unroll
      for (int j = 0; j < 10; ++j)
        Tp2[j] = pk_fma(omb, Tp2[j], pk_mul(gsb, pk_mul(Kcs2[j], uu[j])));
    }
  }
}

extern "C" void kernel_launch(void* const* d_in, const int* in_sizes, int n_in,
                              void* d_out, int out_size, void* d_ws, size_t ws_size,
                              hipStream_t stream) {
  const float* x    = (const float*)d_in[0];
  const int*   ei   = (const int*)d_in[1];
  const float* tmpl = (const float*)d_in[2];
  const float* tf   = (const float*)d_in[3];
  float* out = (float*)d_out;

  int* cnt  = (int*)d_ws;
  int* ebuf = cnt + NNODE;
  int* nbrs = ebuf + (size_t)NNODE * CAP;
  int* kcnt = nbrs + (size_t)NNODE * KNB;
  int* Sg   = kcnt + NNODE;
  unsigned int* bits = (unsigned int*)(Sg + (size_t)NNODE * K1);
  float* Ag   = (float*)(bits + (size_t)NNODE * K1);
  float* dots = Ag + (size_t)NNODE * K1;
  float* nxv  = dots + (size_t)NNODE * (NT * TN);
  float* nF2  = nxv + NNODE;
  float* Bq   = nF2 + NT * TN;

  hipMemsetAsync(cnt, 0, NNODE * sizeof(int), stream);
  k_prep<<<625 + (NNODE + 15) / 16, 256, 0, stream>>>(ei, cnt, ebuf, x, tf, tmpl,
                                                      dots, nxv, nF2, Bq);
  k_select<<<(NNODE + 3) / 4, 256, 0, stream>>>(ei, cnt, ebuf, nbrs, kcnt, Sg);
  k_c1b<<<(NNODE * K1 + 255) / 256, 256, 0, stream>>>(nbrs, kcnt, Sg, bits, Ag);
  k_main<<<NNODE, 128, 0, stream>>>(tmpl, kcnt, Sg, bits, Ag, dots, nxv, nF2, Bq, out);
}